// Round 5
// baseline (825.590 us; speedup 1.0000x reference)
//
#include <hip/hip_runtime.h>
#include <math.h>

constexpr int B = 16, S = 1024, D = 256, E = 64, H = 8, HD = 32;

typedef __attribute__((ext_vector_type(8))) short bf16x8;
typedef __attribute__((ext_vector_type(4))) short bf16x4;
typedef __attribute__((ext_vector_type(4))) float f32x4;

__device__ __forceinline__ float gelu_f(float x) {
  return 0.5f * x * (1.0f + erff(x * 0.70710678118654752440f));
}

__device__ __forceinline__ unsigned short f2bf(float f) {
  union { float f; unsigned u; } x; x.f = f;
  unsigned r = x.u + 0x7fff + ((x.u >> 16) & 1);
  return (unsigned short)(r >> 16);
}

// packed f32x2 -> bf16x2 (RNE), low half = a, high half = b
__device__ __forceinline__ unsigned cvt_pk_bf16(float a, float b) {
  unsigned r;
  asm("v_cvt_pk_bf16_f32 %0, %1, %2" : "=v"(r) : "v"(a), "v"(b));
  return r;
}

// async global->LDS, 16B per lane; lds must be wave-uniform-base + lane*16
__device__ __forceinline__ void gl16(const void* g, void* l) {
  __builtin_amdgcn_global_load_lds(
      (const __attribute__((address_space(1))) void*)g,
      (__attribute__((address_space(3))) void*)l, 16, 0, 0);
}

// ---------------- fp32 -> bf16 conversion: ALL weights in one kernel ----------------
// dst regions are laid out contiguously in wbf: qkv | out | f1 | f2 | v
__global__ void k_cvt_all(const float* __restrict__ s0, const float* __restrict__ s1,
                          const float* __restrict__ s2, const float* __restrict__ s3,
                          const float* __restrict__ s4, unsigned short* __restrict__ dst) {
  int i = (blockIdx.x * 256 + threadIdx.x) * 4;
  const float* src;
  int off;
  if (i < 589824)       { src = s0; off = i; }
  else if (i < 786432)  { src = s1; off = i - 589824; }
  else if (i < 1572864) { src = s2; off = i - 786432; }
  else if (i < 2359296) { src = s3; off = i - 1572864; }
  else                  { src = s4; off = i - 2359296; }
  float4 v = *(const float4*)(src + off);
  dst[i + 0] = f2bf(v.x);
  dst[i + 1] = f2bf(v.y);
  dst[i + 2] = f2bf(v.z);
  dst[i + 3] = f2bf(v.w);
}

// ---------------- embedding: x = tok_emb[tok] + pos_emb[s], vectorized ----------------
// 4 rows per block, float4 per thread.
__global__ void k_embed(const int* __restrict__ tok,
                        const float* __restrict__ tok_emb,
                        const float* __restrict__ pos_emb,
                        float* __restrict__ x, unsigned short* __restrict__ xb) {
  int t = threadIdx.x;
  int r = blockIdx.x * 4 + (t >> 6);
  int c4 = (t & 63) * 4;
  int s = r & (S - 1);
  int tk = tok[r];
  float4 te = *(const float4*)(tok_emb + (size_t)tk * D + c4);
  float4 pe = *(const float4*)(pos_emb + (size_t)s * D + c4);
  float4 v = make_float4(te.x + pe.x, te.y + pe.y, te.z + pe.z, te.w + pe.w);
  *(float4*)(x + (size_t)r * D + c4) = v;
  unsigned lo = cvt_pk_bf16(v.x, v.y), hi = cvt_pk_bf16(v.z, v.w);
  *(uint2*)(xb + (size_t)r * D + c4) = make_uint2(lo, hi);
}

// ---------------- fused side path: enc(x3) -> fusion -> ca(x3 layers) ----------------
// One block per batch element b, 256 threads (= feature dim).
__global__ __launch_bounds__(256)
void k_side(const float* __restrict__ tr, const float* __restrict__ ctx,
            const float* __restrict__ card,
            const float* __restrict__ enc_w, const float* __restrict__ enc_b,
            const float* __restrict__ eg, const float* __restrict__ ebt,
            const float* __restrict__ fw, const float* __restrict__ fb,
            const float* __restrict__ fg, const float* __restrict__ fbt,
            const float* __restrict__ ca_in_w, const float* __restrict__ ca_in_b,
            const float* __restrict__ ca_out_w, const float* __restrict__ ca_out_b,
            float* __restrict__ ca_add) {
  int b = blockIdx.x, d = threadIdx.x;
  __shared__ float catl[768], meml[256], vs[256];
  __shared__ float rw1[4], rw2[4];

  auto lnstat = [&](float acc, float& mean, float& rstd) {
    float a1 = acc, a2 = acc * acc;
#pragma unroll
    for (int off = 32; off > 0; off >>= 1) {
      a1 += __shfl_xor(a1, off);
      a2 += __shfl_xor(a2, off);
    }
    int wid = d >> 6, lane = d & 63;
    if (lane == 0) { rw1[wid] = a1; rw2[wid] = a2; }
    __syncthreads();
    float s1 = rw1[0] + rw1[1] + rw1[2] + rw1[3];
    float s2 = rw2[0] + rw2[1] + rw2[2] + rw2[3];
    mean = s1 * (1.0f / D);
    float var = s2 * (1.0f / D) - mean * mean;
    rstd = rsqrtf(var + 1e-5f);
    __syncthreads();  // safe to rewrite rw next call
  };

  // encoders
  for (int i = 0; i < 3; ++i) {
    const float* xin = (i == 0 ? tr : (i == 1 ? ctx : card)) + b * E;
    const float* wr = enc_w + ((size_t)i * D + d) * E;
    float acc = enc_b[i * D + d];
#pragma unroll 8
    for (int e = 0; e < E; ++e) acc += xin[e] * wr[e];
    float mean, rstd;
    lnstat(acc, mean, rstd);
    float nv = (acc - mean) * rstd * eg[i * D + d] + ebt[i * D + d];
    catl[i * D + d] = gelu_f(nv);
  }
  __syncthreads();  // catl complete

  // fusion
  {
    const float* fwr = fw + (size_t)d * 768;
    float fa = fb[d];
    for (int k = 0; k < 768; ++k) fa += catl[k] * fwr[k];
    float mean, rstd;
    lnstat(fa, mean, rstd);
    meml[d] = gelu_f((fa - mean) * rstd * fg[d] + fbt[d]);
  }
  __syncthreads();  // meml complete

  // cross-attn collapsed (softmax over single key == identity), per layer
  for (int l = 0; l < 3; ++l) {
    const float* wi = ca_in_w + ((size_t)l * 768 + 512 + d) * 256;
    float v = ca_in_b[l * 768 + 512 + d];
    for (int k = 0; k < 256; ++k) v += meml[k] * wi[k];
    vs[d] = v;
    __syncthreads();
    const float* wo = ca_out_w + ((size_t)l * 256 + d) * 256;
    float o = ca_out_b[l * 256 + d];
    for (int k = 0; k < 256; ++k) o += vs[k] * wo[k];
    ca_add[((size_t)l * B + b) * 256 + d] = o;
    __syncthreads();  // vs rewrite next l
  }
}

// ---------------- causal flash attention via MFMA, swapped-QK^T softmax ----------------
// 8 waves x 32 queries = 256 queries per block for one (b,h). KT=64 keys/step.
// K/V staged ONCE per block per step; defer-max (T13).
// QK^T computed as mfma(K,Q): C col=lane&15 = q, row=(lane>>4)*4+reg = k.
__global__ __launch_bounds__(512)
void k_attn6(const unsigned short* __restrict__ qkv, unsigned short* __restrict__ out) {
  constexpr int KT = 64;
  __shared__ unsigned short Ks[2][KT * 32];   // [key][32] linear (gl16 dest)
  __shared__ unsigned short Vt[2][32 * KT];   // [d][key], XOR-swizzled rows
  __shared__ unsigned short Pl[8 * 32 * KT];  // per-wave P [q][k], XOR-swizzled

  const int t = threadIdx.x;
  const int w = t >> 6, lane = t & 63;
  const int lg = lane >> 4, lr = lane & 15;
  const int bh = blockIdx.y;
  const int h = bh & (H - 1), b = bh >> 3;
  const int qtile = (int)gridDim.x - 1 - (int)blockIdx.x;  // biggest tiles first
  const int qb = qtile << 8;    // 256 queries per block
  const int qw = qb + w * 32;   // wave query base
  const unsigned short* base = qkv + (size_t)b * S * 768 + h * HD;

  bf16x8 qf[2];
#pragma unroll
  for (int qr = 0; qr < 2; ++qr)
    qf[qr] = *(const bf16x8*)(base + (size_t)(qw + qr * 16 + lr) * 768 + lg * 8);

  f32x4 o[2][2];
#pragma unroll
  for (int qr = 0; qr < 2; ++qr)
#pragma unroll
    for (int dt = 0; dt < 2; ++dt) o[qr][dt] = (f32x4){0.f, 0.f, 0.f, 0.f};
  float mq[2], lq[2];
#pragma unroll
  for (int qr = 0; qr < 2; ++qr) { mq[qr] = -3.0e38f; lq[qr] = 0.f; }

  const float Cs = 0.17677669529663687f * 1.4426950408889634f;  // 1/sqrt(32)*log2(e)

  const int skey = t >> 2;
  const int sch = (t & 3) * 8;
  const int vkey = t >> 3;
  const int vch = (t & 7) * 4;
  char* pbase = (char*)Pl + (w << 12);

  const int nkt = (qb + 256) >> 6;  // 4,8,12,16

  if (t < 256) gl16(base + (size_t)skey * 768 + 256 + sch, (char*)Ks[0] + t * 16);
  bf16x4 vv = *(const bf16x4*)(base + (size_t)vkey * 768 + 512 + vch);
  __syncthreads();

  for (int kti = 0; kti < nkt; ++kti) {
    const int kt = kti << 6;
    const int cur = kti & 1;

#pragma unroll
    for (int j = 0; j < 4; ++j) {
      int d = vch + j;
      int byteo = d * (KT * 2) + ((vkey * 2) ^ ((d & 7) << 4));
      *(unsigned short*)((char*)Vt[cur] + byteo) = (unsigned short)vv[j];
    }
    if (kti + 1 < nkt) {
      if (t < 256)
        gl16(base + (size_t)(kt + KT + skey) * 768 + 256 + sch, (char*)Ks[cur ^ 1] + t * 16);
      vv = *(const bf16x4*)(base + (size_t)(kt + KT + vkey) * 768 + 512 + vch);
    }

    const bool active = (kt <= qw + 31);
    if (active) {
      bf16x8 kf[4];
#pragma unroll
      for (int t4 = 0; t4 < 4; ++t4)
        kf[t4] = *(const bf16x8*)&Ks[cur][(t4 * 16 + lr) * 32 + lg * 8];
      f32x4 sc[2][4];
      __builtin_amdgcn_s_setprio(1);
#pragma unroll
      for (int qr = 0; qr < 2; ++qr)
#pragma unroll
        for (int t4 = 0; t4 < 4; ++t4)
          sc[qr][t4] = __builtin_amdgcn_mfma_f32_16x16x32_bf16(
              kf[t4], qf[qr], (f32x4){0.f, 0.f, 0.f, 0.f}, 0, 0, 0);
      __builtin_amdgcn_s_setprio(0);

      if (kt + KT > qw) {
#pragma unroll
        for (int qr = 0; qr < 2; ++qr) {
          int q = qw + qr * 16 + lr;
#pragma unroll
          for (int t4 = 0; t4 < 4; ++t4)
#pragma unroll
            for (int r = 0; r < 4; ++r) {
              int k = kt + t4 * 16 + lg * 4 + r;
              if (k > q) sc[qr][t4][r] = -3.0e38f;
            }
        }
      }

#pragma unroll
      for (int qr = 0; qr < 2; ++qr) {
        float mx = sc[qr][0][0];
#pragma unroll
        for (int t4 = 0; t4 < 4; ++t4)
#pragma unroll
          for (int r = 0; r < 4; ++r) mx = fmaxf(mx, sc[qr][t4][r]);
        mx = fmaxf(mx, __shfl_xor(mx, 16));
        mx = fmaxf(mx, __shfl_xor(mx, 32));
        if (__any(mx > mq[qr] + 8.0f)) {
          float mn = fmaxf(mx, mq[qr]);
          float cf = exp2f((mq[qr] - mn) * Cs);
          mq[qr] = mn;
          lq[qr] *= cf;
#pragma unroll
          for (int r = 0; r < 4; ++r) {
            float cfo = __shfl(cf, (lane & 48) | (lg * 4 + r));
            o[qr][0][r] *= cfo;
            o[qr][1][r] *= cfo;
          }
        }
        float nmxC = -mq[qr] * Cs;
        float ps = 0.f;
#pragma unroll
        for (int t4 = 0; t4 < 4; ++t4)
#pragma unroll
          for (int r = 0; r < 4; ++r) {
            float p = exp2f(fmaf(sc[qr][t4][r], Cs, nmxC));
            sc[qr][t4][r] = p;
            ps += p;
          }
        lq[qr] += ps;
        int ql = qr * 16 + lr;
        int swz = (ql & 7) << 4;
        char* prow = pbase + ql * (KT * 2);
#pragma unroll
        for (int t4 = 0; t4 < 4; ++t4) {
          unsigned lo = cvt_pk_bf16(sc[qr][t4][0], sc[qr][t4][1]);
          unsigned hi = cvt_pk_bf16(sc[qr][t4][2], sc[qr][t4][3]);
          *(uint2*)(prow + ((t4 * 32 + lg * 8) ^ swz)) = make_uint2(lo, hi);
        }
      }
    }

    __syncthreads();

    if (active) {
#pragma unroll
      for (int kp = 0; kp < 2; ++kp) {
        bf16x8 vf[2], pf[2];
        int kb = kp * 64 + lg * 16;
#pragma unroll
        for (int dt = 0; dt < 2; ++dt) {
          int d = dt * 16 + lr;
          vf[dt] = *(const bf16x8*)((char*)Vt[cur] + d * (KT * 2) + (kb ^ ((d & 7) << 4)));
        }
#pragma unroll
        for (int qr = 0; qr < 2; ++qr) {
          int ql = qr * 16 + lr;
          pf[qr] = *(const bf16x8*)(pbase + ql * (KT * 2) + (kb ^ ((ql & 7) << 4)));
        }
        __builtin_amdgcn_s_setprio(1);
#pragma unroll
        for (int qr = 0; qr < 2; ++qr)
#pragma unroll
          for (int dt = 0; dt < 2; ++dt)
            o[qr][dt] = __builtin_amdgcn_mfma_f32_16x16x32_bf16(
                pf[qr], vf[dt], o[qr][dt], 0, 0, 0);
        __builtin_amdgcn_s_setprio(0);
      }
    }
  }

#pragma unroll
  for (int qr = 0; qr < 2; ++qr) {
    float ls = lq[qr];
    ls += __shfl_xor(ls, 16);
    ls += __shfl_xor(ls, 32);
    float invq = 1.0f / ls;
#pragma unroll
    for (int r = 0; r < 4; ++r) {
      float inv = __shfl(invq, (lane & 48) | (lg * 4 + r));
      int q = qw + qr * 16 + lg * 4 + r;
      unsigned short* orow = out + (size_t)(b * S + q) * D + h * HD;
#pragma unroll
      for (int dt = 0; dt < 2; ++dt)
        orow[dt * 16 + lr] = f2bf(o[qr][dt][r] * inv);
    }
  }
}

// ---------------- bf16 MFMA GEMM: C[M,N] = A[M,K] @ W[N,K]^T + bias ----------------
// 128x128 tile, BK=32. EPI: 0=none 1=relu. OUTBF: fp32/bf16 out. SWZ: XCD block swizzle.
template <int EPI, int OUTBF, int SWZ>
__global__ __launch_bounds__(256)
void k_gemm_mfma(const unsigned short* __restrict__ A,
                 const unsigned short* __restrict__ W,
                 const float* __restrict__ bias,
                 void* __restrict__ Cout,
                 int M, int N, int K) {
  __shared__ unsigned short As[128][32];
  __shared__ unsigned short Bs[128][32];
  int t = threadIdx.x;
  int bx = blockIdx.x, by = blockIdx.y;
  if (SWZ) {
    // contiguous row-major chunk per XCD (requires nwg % 8 == 0)
    int nx = gridDim.x;
    int lin = by * nx + bx;
    int q = (nx * (int)gridDim.y) >> 3;
    int nl = (lin & 7) * q + (lin >> 3);
    by = nl / nx;
    bx = nl - by * nx;
  }
  int row0 = by * 128, col0 = bx * 128;
  int wid = t >> 6, lane = t & 63;
  int wr = wid >> 1, wc = wid & 1;
  int lrow = lane & 15, lko = (lane >> 4) * 8;

  f32x4 acc[4][4];
#pragma unroll
  for (int mi = 0; mi < 4; ++mi)
#pragma unroll
    for (int ni = 0; ni < 4; ++ni)
      acc[mi][ni] = (f32x4){0.f, 0.f, 0.f, 0.f};

  int c0 = t, c1 = t + 256;
  int ar0 = c0 >> 2, aq0 = (c0 & 3) * 8;
  int ar1 = c1 >> 2, aq1 = (c1 & 3) * 8;
  int wrow0 = col0 + ar0; if (wrow0 > N - 1) wrow0 = N - 1;
  int wrow1 = col0 + ar1; if (wrow1 > N - 1) wrow1 = N - 1;

  const unsigned short* A0 = A + (size_t)(row0 + ar0) * K + aq0;
  const unsigned short* A1 = A + (size_t)(row0 + ar1) * K + aq1;
  const unsigned short* W0 = W + (size_t)wrow0 * K + aq0;
  const unsigned short* W1 = W + (size_t)wrow1 * K + aq1;

  for (int kt = 0; kt < K; kt += 32) {
    gl16(A0 + kt, (char*)As + c0 * 16);
    gl16(A1 + kt, (char*)As + c1 * 16);
    gl16(W0 + kt, (char*)Bs + c0 * 16);
    gl16(W1 + kt, (char*)Bs + c1 * 16);
    __syncthreads();

    bf16x8 af[4], bfr[4];
#pragma unroll
    for (int mi = 0; mi < 4; ++mi)
      af[mi] = *(const bf16x8*)&As[wr * 64 + mi * 16 + lrow][lko];
#pragma unroll
    for (int ni = 0; ni < 4; ++ni)
      bfr[ni] = *(const bf16x8*)&Bs[wc * 64 + ni * 16 + lrow][lko];
#pragma unroll
    for (int mi = 0; mi < 4; ++mi)
#pragma unroll
      for (int ni = 0; ni < 4; ++ni)
        acc[mi][ni] = __builtin_amdgcn_mfma_f32_16x16x32_bf16(af[mi], bfr[ni], acc[mi][ni], 0, 0, 0);
    __syncthreads();
  }

  int rbase = row0 + wr * 64 + (lane >> 4) * 4;
  int cbase = col0 + wc * 64 + lrow;
#pragma unroll
  for (int ni = 0; ni < 4; ++ni) {
    int c = cbase + ni * 16;
    if (c < N) {
      float bv = bias[c];
#pragma unroll
      for (int mi = 0; mi < 4; ++mi) {
        int rr = rbase + mi * 16;
#pragma unroll
        for (int r = 0; r < 4; ++r) {
          float v = acc[mi][ni][r] + bv;
          if (EPI == 1) v = fmaxf(v, 0.0f);
          size_t off = (size_t)(rr + r) * N + c;
          if (OUTBF)
            ((unsigned short*)Cout)[off] = f2bf(v);
          else
            ((float*)Cout)[off] = v;
        }
      }
    }
  }
}

// ---------------- fused GEMM (N=256) + residual + 1 or 2 LayerNorms ----------------
// Tile 64 rows x 256 cols, 4 waves, BK=32. Grid = 256 blocks = 1/CU -> deep in-block
// pipeline: ring-4 LDS buffers, 2-step prefetch, counted vmcnt (T3/T4), one raw
// s_barrier per step (never drain vmcnt to 0 in the main loop).
template <int NLN>
__global__ __launch_bounds__(256)
void k_gemm_ln(const unsigned short* __restrict__ A,
               const unsigned short* __restrict__ W,
               const float* __restrict__ bias,
               const float* __restrict__ res,
               const float* __restrict__ ca,
               const float* __restrict__ g1, const float* __restrict__ b1,
               const float* __restrict__ g2, const float* __restrict__ b2,
               float* __restrict__ xout, unsigned short* __restrict__ xb,
               int K) {
  __shared__ unsigned short As[4][64][32];    // 16 KB
  __shared__ unsigned short Bs[4][256][32];   // 64 KB
  __shared__ float red[2][64][4];
  int t = threadIdx.x;
  int row0 = blockIdx.x * 64;
  int wc = t >> 6, lane = t & 63;
  int lr = lane & 15, lg = lane >> 4;

  f32x4 acc[4][4];
#pragma unroll
  for (int mi = 0; mi < 4; ++mi)
#pragma unroll
    for (int ni = 0; ni < 4; ++ni)
      acc[mi][ni] = (f32x4){0.f, 0.f, 0.f, 0.f};

  // staging: 5 x 16B chunks per thread per step. chunk 0 -> As, chunks 1..4 -> Bs.
  int arw = t >> 2, aq = (t & 3) * 8;
  const unsigned short* srcA = A + (size_t)(row0 + arw) * K + aq;
  int adoff = t * 16;
  const unsigned short* srcB[4];
  int bdoff[4];
#pragma unroll
  for (int j = 0; j < 4; ++j) {
    int cb = t + (j << 8);
    int rw = cb >> 2, q = (cb & 3) * 8;
    srcB[j] = W + (size_t)rw * K + q;
    bdoff[j] = cb * 16;
  }

  auto stage = [&](int s) {
    int slot = s & 3;
    int off = s << 5;
    gl16(srcA + off, (char*)As[slot] + adoff);
#pragma unroll
    for (int j = 0; j < 4; ++j) gl16(srcB[j] + off, (char*)Bs[slot] + bdoff[j]);
  };

  const int nsteps = K >> 5;  // 8 or 32
  stage(0);
  stage(1);
  for (int s = 0; s < nsteps; ++s) {
    if (s + 2 < nsteps) {
      stage(s + 2);
      asm volatile("s_waitcnt vmcnt(10)" ::: "memory");  // 2 newer stages in flight
    } else if (s + 1 < nsteps) {
      asm volatile("s_waitcnt vmcnt(5)" ::: "memory");   // 1 newer stage in flight
    } else {
      asm volatile("s_waitcnt vmcnt(0)" ::: "memory");
    }
    __builtin_amdgcn_s_barrier();
    __builtin_amdgcn_sched_barrier(0);
    int slot = s & 3;
    bf16x8 af[4], bfr[4];
#pragma unroll
    for (int mi = 0; mi < 4; ++mi)
      af[mi] = *(const bf16x8*)&As[slot][mi * 16 + lr][lg * 8];
#pragma unroll
    for (int ni = 0; ni < 4; ++ni)
      bfr[ni] = *(const bf16x8*)&Bs[slot][wc * 64 + ni * 16 + lr][lg * 8];
    __builtin_amdgcn_s_setprio(1);
#pragma unroll
    for (int mi = 0; mi < 4; ++mi)
#pragma unroll
      for (int ni = 0; ni < 4; ++ni)
        acc[mi][ni] = __builtin_amdgcn_mfma_f32_16x16x32_bf16(af[mi], bfr[ni], acc[mi][ni], 0, 0, 0);
    __builtin_amdgcn_s_setprio(0);
  }

  // ---- epilogue: v = acc + bias + res; LN over the full 256-col row ----
  int colb = wc * 64 + lr;
  float mean[4][4], rstd[4][4];

#pragma unroll
  for (int mi = 0; mi < 4; ++mi) {
#pragma unroll
    for (int r = 0; r < 4; ++r) {
      int rowl = mi * 16 + lg * 4 + r;
      int rowg = row0 + rowl;
      float s1 = 0.f, s2 = 0.f;
#pragma unroll
      for (int ni = 0; ni < 4; ++ni) {
        int c = colb + ni * 16;
        float v = acc[mi][ni][r] + bias[c] + res[(size_t)rowg * D + c];
        acc[mi][ni][r] = v;
        s1 += v; s2 += v * v;
      }
#pragma unroll
      for (int msk = 1; msk <= 8; msk <<= 1) {
        s1 += __shfl_xor(s1, msk);
        s2 += __shfl_xor(s2, msk);
      }
      if (lr == 0) { red[0][rowl][wc] = s1; red[1][rowl][wc] = s2; }
    }
  }
  __syncthreads();
#pragma unroll
  for (int mi = 0; mi < 4; ++mi)
#pragma unroll
    for (int r = 0; r < 4; ++r) {
      int rowl = mi * 16 + lg * 4 + r;
      f32x4 a = *(const f32x4*)&red[0][rowl][0];
      f32x4 bq = *(const f32x4*)&red[1][rowl][0];
      float s1 = a[0] + a[1] + a[2] + a[3];
      float s2 = bq[0] + bq[1] + bq[2] + bq[3];
      float mn = s1 * (1.0f / D);
      float vr = s2 * (1.0f / D) - mn * mn;
      mean[mi][r] = mn;
      rstd[mi][r] = rsqrtf(vr + 1e-5f);
    }
#pragma unroll
  for (int mi = 0; mi < 4; ++mi)
#pragma unroll
    for (int ni = 0; ni < 4; ++ni) {
      int c = colb + ni * 16;
      float gg = g1[c], bb = b1[c];
#pragma unroll
      for (int r = 0; r < 4; ++r)
        acc[mi][ni][r] = (acc[mi][ni][r] - mean[mi][r]) * rstd[mi][r] * gg + bb;
    }

  if (NLN == 2) {
    __syncthreads();
#pragma unroll
    for (int mi = 0; mi < 4; ++mi) {
#pragma unroll
      for (int r = 0; r < 4; ++r) {
        int rowl = mi * 16 + lg * 4 + r;
        int rowg = row0 + rowl;
        int bidx = rowg >> 10;  // row / S
        float s1 = 0.f, s2 = 0.f;
#pragma unroll
        for (int ni = 0; ni < 4; ++ni) {
          int c = colb + ni * 16;
          float v = acc[mi][ni][r] + ca[(size_t)bidx * D + c];
          acc[mi][ni][r] = v;
          s1 += v; s2 += v * v;
        }
#pragma unroll
        for (int msk = 1; msk <= 8; msk <<= 1) {
          s1 += __shfl_xor(s1, msk);
          s2 += __shfl_xor(s2, msk);
        }
        if (lr == 0) { red[0][rowl][wc] = s1; red[1][rowl][wc] = s2; }
      }
    }
    __syncthreads();
#pragma unroll
    for (int mi = 0; mi < 4; ++mi)
#pragma unroll
      for (int r = 0; r < 4; ++r) {
        int rowl = mi * 16 + lg * 4 + r;
        f32x4 a = *(const f32x4*)&red[0][rowl][0];
        f32x4 bq = *(const f32x4*)&red[1][rowl][0];
        float s1 = a[0] + a[1] + a[2] + a[3];
        float s2 = bq[0] + bq[1] + bq[2] + bq[3];
        float mn = s1 * (1.0f / D);
        float vr = s2 * (1.0f / D) - mn * mn;
        mean[mi][r] = mn;
        rstd[mi][r] = rsqrtf(vr + 1e-5f);
      }
#pragma unroll
    for (int mi = 0; mi < 4; ++mi)
#pragma unroll
      for (int ni = 0; ni < 4; ++ni) {
        int c = colb + ni * 16;
        float gg = g2[c], bb = b2[c];
#pragma unroll
        for (int r = 0; r < 4; ++r)
          acc[mi][ni][r] = (acc[mi][ni][r] - mean[mi][r]) * rstd[mi][r] * gg + bb;
      }
  }

#pragma unroll
  for (int mi = 0; mi < 4; ++mi)
#pragma unroll
    for (int r = 0; r < 4; ++r) {
      int rowg = row0 + mi * 16 + lg * 4 + r;
#pragma unroll
      for (int ni = 0; ni < 4; ++ni) {
        int c = colb + ni * 16;
        float v = acc[mi][ni][r];
        xout[(size_t)rowg * D + c] = v;
        xb[(size_t)rowg * D + c] = f2bf(v);
      }
    }
}

extern "C" void kernel_launch(void* const* d_in, const int* in_sizes, int n_in,
                              void* d_out, int out_size, void* d_ws, size_t ws_size,
                              hipStream_t stream) {
  (void)in_sizes; (void)n_in; (void)out_size; (void)ws_size;
  const float* tractovka = (const float*)d_in[0];
  const float* context   = (const float*)d_in[1];
  const float* card      = (const float*)d_in[2];
  const float* enc_w     = (const float*)d_in[3];
  const float* enc_b     = (const float*)d_in[4];
  const float* enc_ln_g  = (const float*)d_in[5];
  const float* enc_ln_b  = (const float*)d_in[6];
  const float* fusion_w  = (const float*)d_in[7];
  const float* fusion_b  = (const float*)d_in[8];
  const float* fusion_ln_g = (const float*)d_in[9];
  const float* fusion_ln_b = (const float*)d_in[10];
  const float* tok_emb   = (const float*)d_in[11];
  const float* pos_emb   = (const float*)d_in[12];
  const float* sa_in_w   = (const float*)d_in[13];
  const float* sa_in_b   = (const float*)d_in[14];
  const float* sa_out_w  = (const float*)d_in[15];
  const float* sa_out_b  = (const float*)d_in[16];
  const float* ca_in_w   = (const float*)d_in[17];
  const float* ca_in_b   = (const float*)d_in[18];
  const float* ca_out_w  = (const float*)d_in[19];
  const float* ca_out_b  = (const float*)d_in[20];
  const float* ln1_g     = (const float*)d_in[21];
  const float* ln1_b     = (const float*)d_in[22];
  const float* ln2_g     = (const float*)d_in[23];
  const float* ln2_b     = (const float*)d_in[24];
  const float* ln3_g     = (const float*)d_in[25];
  const float* ln3_b     = (const float*)d_in[26];
  const float* ffn_w1    = (const float*)d_in[27];
  const float* ffn_b1    = (const float*)d_in[28];
  const float* ffn_w2    = (const float*)d_in[29];
  const float* ffn_b2    = (const float*)d_in[30];
  const float* out_w     = (const float*)d_in[31];
  const float* out_b     = (const float*)d_in[32];
  const int*   prev      = (const int*)d_in[33];
  float* out = (float*)d_out;

  const int M = B * S;  // 16384

  float* ws = (float*)d_ws;
  float* x      = ws;                        // M*D f32
  float* bufA   = x + (size_t)M * D;         // M*768 region (QKV bf16; aliased by ffn1b)
  float* bufB   = bufA + (size_t)M * 768;    // M*D f32 (unused, kept for layout)
  float* cat    = bufB + (size_t)M * D;      // B*3D (unused, kept for layout)
  float* mem    = cat + (size_t)B * 3 * D;   // B*D (unused, kept for layout)
  float* ca_add = mem + (size_t)B * D;       // 3*B*D
  unsigned short* xb    = (unsigned short*)(ca_add + (size_t)3 * B * D);  // M*D bf16
  unsigned short* attnb = xb + (size_t)M * D;                             // M*D bf16
  unsigned short* wbf   = attnb + (size_t)M * D;                          // weights bf16
  unsigned short* qkvb  = (unsigned short*)bufA;                          // M*768 bf16
  unsigned short* ffn1b = (unsigned short*)bufA;                          // M*1024 bf16

  const int n_qkvw = 3 * 768 * D;    // 589824
  const int n_outw = 3 * D * D;      // 196608
  const int n_f1w  = 3 * 1024 * D;   // 786432
  const int n_f2w  = 3 * D * 1024;   // 786432
  unsigned short* w_qkv = wbf;
  unsigned short* w_out = w_qkv + n_qkvw;
  unsigned short* w_f1  = w_out + n_outw;
  unsigned short* w_f2  = w_f1 + n_f1w;
  unsigned short* w_v   = w_f2 + n_f2w;

  // all weight conversions in one kernel (dst regions contiguous in wbf)
  k_cvt_all<<<4804, 256, 0, stream>>>(sa_in_w, sa_out_w, ffn_w1, ffn_w2, out_w, wbf);

  // embedding (+bf16 shadow), vectorized
  k_embed<<<M / 4, 256, 0, stream>>>(prev, tok_emb, pos_emb, x, xb);
  // fused encoder side path: enc x3 -> fusion -> ca x3
  k_side<<<B, 256, 0, stream>>>(tractovka, context, card,
                                enc_w, enc_b, enc_ln_g, enc_ln_b,
                                fusion_w, fusion_b, fusion_ln_g, fusion_ln_b,
                                ca_in_w, ca_in_b, ca_out_w, ca_out_b, ca_add);

  for (int l = 0; l < 3; ++l) {
    // QKV: [M,256]@[768,256]^T -> qkvb bf16 [M,768]
    k_gemm_mfma<0, 1, 0><<<dim3(6, M / 128), 256, 0, stream>>>(
        xb, w_qkv + (size_t)l * 768 * D, sa_in_b + (size_t)l * 3 * D, qkvb,
        M, 768, D);
    // causal self-attention (MFMA flash, 256q/block, defer-max) -> attnb bf16
    k_attn6<<<dim3(S / 256, B * H), 512, 0, stream>>>(qkvb, attnb);
    // out-proj + LN1 + (+ca_add) + LN2 fused -> x fp32, xb bf16
    k_gemm_ln<2><<<dim3(M / 64), 256, 0, stream>>>(
        attnb, w_out + (size_t)l * D * D, sa_out_b + (size_t)l * D,
        x, ca_add + (size_t)l * B * D,
        ln1_g + (size_t)l * D, ln1_b + (size_t)l * D,
        ln2_g + (size_t)l * D, ln2_b + (size_t)l * D,
        x, xb, D);
    // FFN1: relu(x@w1^T+b1) -> ffn1b bf16 [M,1024]
    k_gemm_mfma<1, 1, 0><<<dim3(8, M / 128), 256, 0, stream>>>(
        xb, w_f1 + (size_t)l * 1024 * D, ffn_b1 + (size_t)l * 4 * D, ffn1b,
        M, 1024, D);
    // FFN2 + LN3 fused -> x fp32, xb bf16
    k_gemm_ln<1><<<dim3(M / 64), 256, 0, stream>>>(
        ffn1b, w_f2 + (size_t)l * D * 1024, ffn_b2 + (size_t)l * D,
        x, nullptr,
        ln3_g + (size_t)l * D, ln3_b + (size_t)l * D,
        nullptr, nullptr,
        x, xb, 1024);
  }
  // final vocab projection: [M,256]@[10000,256]^T -> out fp32 (XCD-swizzled)
  k_gemm_mfma<0, 0, 1><<<dim3(79, M / 128), 256, 0, stream>>>(
      xb, w_v, out_b, out, M, 10000, D);
}

// Round 6
// 806.816 us; speedup vs baseline: 1.0233x; 1.0233x over previous
//
#include <hip/hip_runtime.h>
#include <math.h>

constexpr int B = 16, S = 1024, D = 256, E = 64, H = 8, HD = 32;

typedef __attribute__((ext_vector_type(8))) short bf16x8;
typedef __attribute__((ext_vector_type(4))) short bf16x4;
typedef __attribute__((ext_vector_type(4))) float f32x4;

__device__ __forceinline__ float gelu_f(float x) {
  return 0.5f * x * (1.0f + erff(x * 0.70710678118654752440f));
}

__device__ __forceinline__ unsigned short f2bf(float f) {
  union { float f; unsigned u; } x; x.f = f;
  unsigned r = x.u + 0x7fff + ((x.u >> 16) & 1);
  return (unsigned short)(r >> 16);
}

// packed f32x2 -> bf16x2 (RNE), low half = a, high half = b
__device__ __forceinline__ unsigned cvt_pk_bf16(float a, float b) {
  unsigned r;
  asm("v_cvt_pk_bf16_f32 %0, %1, %2" : "=v"(r) : "v"(a), "v"(b));
  return r;
}

// async global->LDS, 16B per lane; lds must be wave-uniform-base + lane*16
__device__ __forceinline__ void gl16(const void* g, void* l) {
  __builtin_amdgcn_global_load_lds(
      (const __attribute__((address_space(1))) void*)g,
      (__attribute__((address_space(3))) void*)l, 16, 0, 0);
}

// ---------------- fp32 -> bf16 conversion: ALL weights in one kernel ----------------
// dst regions are laid out contiguously in wbf: qkv | out | f1 | f2 | v
__global__ void k_cvt_all(const float* __restrict__ s0, const float* __restrict__ s1,
                          const float* __restrict__ s2, const float* __restrict__ s3,
                          const float* __restrict__ s4, unsigned short* __restrict__ dst) {
  int i = (blockIdx.x * 256 + threadIdx.x) * 4;
  const float* src;
  int off;
  if (i < 589824)       { src = s0; off = i; }
  else if (i < 786432)  { src = s1; off = i - 589824; }
  else if (i < 1572864) { src = s2; off = i - 786432; }
  else if (i < 2359296) { src = s3; off = i - 1572864; }
  else                  { src = s4; off = i - 2359296; }
  float4 v = *(const float4*)(src + off);
  dst[i + 0] = f2bf(v.x);
  dst[i + 1] = f2bf(v.y);
  dst[i + 2] = f2bf(v.z);
  dst[i + 3] = f2bf(v.w);
}

// ---------------- embedding: x = tok_emb[tok] + pos_emb[s], vectorized ----------------
// 4 rows per block, float4 per thread.
__global__ void k_embed(const int* __restrict__ tok,
                        const float* __restrict__ tok_emb,
                        const float* __restrict__ pos_emb,
                        float* __restrict__ x, unsigned short* __restrict__ xb) {
  int t = threadIdx.x;
  int r = blockIdx.x * 4 + (t >> 6);
  int c4 = (t & 63) * 4;
  int s = r & (S - 1);
  int tk = tok[r];
  float4 te = *(const float4*)(tok_emb + (size_t)tk * D + c4);
  float4 pe = *(const float4*)(pos_emb + (size_t)s * D + c4);
  float4 v = make_float4(te.x + pe.x, te.y + pe.y, te.z + pe.z, te.w + pe.w);
  *(float4*)(x + (size_t)r * D + c4) = v;
  unsigned lo = cvt_pk_bf16(v.x, v.y), hi = cvt_pk_bf16(v.z, v.w);
  *(uint2*)(xb + (size_t)r * D + c4) = make_uint2(lo, hi);
}

// ---------------- fused side path: enc(x3) -> fusion -> ca(x3 layers) ----------------
// One block per batch element b, 256 threads (= feature dim).
__global__ __launch_bounds__(256)
void k_side(const float* __restrict__ tr, const float* __restrict__ ctx,
            const float* __restrict__ card,
            const float* __restrict__ enc_w, const float* __restrict__ enc_b,
            const float* __restrict__ eg, const float* __restrict__ ebt,
            const float* __restrict__ fw, const float* __restrict__ fb,
            const float* __restrict__ fg, const float* __restrict__ fbt,
            const float* __restrict__ ca_in_w, const float* __restrict__ ca_in_b,
            const float* __restrict__ ca_out_w, const float* __restrict__ ca_out_b,
            float* __restrict__ ca_add) {
  int b = blockIdx.x, d = threadIdx.x;
  __shared__ float catl[768], meml[256], vs[256];
  __shared__ float rw1[4], rw2[4];

  auto lnstat = [&](float acc, float& mean, float& rstd) {
    float a1 = acc, a2 = acc * acc;
#pragma unroll
    for (int off = 32; off > 0; off >>= 1) {
      a1 += __shfl_xor(a1, off);
      a2 += __shfl_xor(a2, off);
    }
    int wid = d >> 6, lane = d & 63;
    if (lane == 0) { rw1[wid] = a1; rw2[wid] = a2; }
    __syncthreads();
    float s1 = rw1[0] + rw1[1] + rw1[2] + rw1[3];
    float s2 = rw2[0] + rw2[1] + rw2[2] + rw2[3];
    mean = s1 * (1.0f / D);
    float var = s2 * (1.0f / D) - mean * mean;
    rstd = rsqrtf(var + 1e-5f);
    __syncthreads();  // safe to rewrite rw next call
  };

  // encoders
  for (int i = 0; i < 3; ++i) {
    const float* xin = (i == 0 ? tr : (i == 1 ? ctx : card)) + b * E;
    const float* wr = enc_w + ((size_t)i * D + d) * E;
    float acc = enc_b[i * D + d];
#pragma unroll 8
    for (int e = 0; e < E; ++e) acc += xin[e] * wr[e];
    float mean, rstd;
    lnstat(acc, mean, rstd);
    float nv = (acc - mean) * rstd * eg[i * D + d] + ebt[i * D + d];
    catl[i * D + d] = gelu_f(nv);
  }
  __syncthreads();  // catl complete

  // fusion
  {
    const float* fwr = fw + (size_t)d * 768;
    float fa = fb[d];
    for (int k = 0; k < 768; ++k) fa += catl[k] * fwr[k];
    float mean, rstd;
    lnstat(fa, mean, rstd);
    meml[d] = gelu_f((fa - mean) * rstd * fg[d] + fbt[d]);
  }
  __syncthreads();  // meml complete

  // cross-attn collapsed (softmax over single key == identity), per layer
  for (int l = 0; l < 3; ++l) {
    const float* wi = ca_in_w + ((size_t)l * 768 + 512 + d) * 256;
    float v = ca_in_b[l * 768 + 512 + d];
    for (int k = 0; k < 256; ++k) v += meml[k] * wi[k];
    vs[d] = v;
    __syncthreads();
    const float* wo = ca_out_w + ((size_t)l * 256 + d) * 256;
    float o = ca_out_b[l * 256 + d];
    for (int k = 0; k < 256; ++k) o += vs[k] * wo[k];
    ca_add[((size_t)l * B + b) * 256 + d] = o;
    __syncthreads();  // vs rewrite next l
  }
}

// ---------------- causal flash attention via MFMA, swapped-QK^T softmax ----------------
// 8 waves x 32 queries = 256 queries per block for one (b,h). KT=64 keys/step.
// K/V staged ONCE per block per step; defer-max (T13).
// QK^T computed as mfma(K,Q): C col=lane&15 = q, row=(lane>>4)*4+reg = k.
__global__ __launch_bounds__(512)
void k_attn6(const unsigned short* __restrict__ qkv, unsigned short* __restrict__ out) {
  constexpr int KT = 64;
  __shared__ unsigned short Ks[2][KT * 32];   // [key][32] linear (gl16 dest)
  __shared__ unsigned short Vt[2][32 * KT];   // [d][key], XOR-swizzled rows
  __shared__ unsigned short Pl[8 * 32 * KT];  // per-wave P [q][k], XOR-swizzled

  const int t = threadIdx.x;
  const int w = t >> 6, lane = t & 63;
  const int lg = lane >> 4, lr = lane & 15;
  const int bh = blockIdx.y;
  const int h = bh & (H - 1), b = bh >> 3;
  const int qtile = (int)gridDim.x - 1 - (int)blockIdx.x;  // biggest tiles first
  const int qb = qtile << 8;    // 256 queries per block
  const int qw = qb + w * 32;   // wave query base
  const unsigned short* base = qkv + (size_t)b * S * 768 + h * HD;

  bf16x8 qf[2];
#pragma unroll
  for (int qr = 0; qr < 2; ++qr)
    qf[qr] = *(const bf16x8*)(base + (size_t)(qw + qr * 16 + lr) * 768 + lg * 8);

  f32x4 o[2][2];
#pragma unroll
  for (int qr = 0; qr < 2; ++qr)
#pragma unroll
    for (int dt = 0; dt < 2; ++dt) o[qr][dt] = (f32x4){0.f, 0.f, 0.f, 0.f};
  float mq[2], lq[2];
#pragma unroll
  for (int qr = 0; qr < 2; ++qr) { mq[qr] = -3.0e38f; lq[qr] = 0.f; }

  const float Cs = 0.17677669529663687f * 1.4426950408889634f;  // 1/sqrt(32)*log2(e)

  const int skey = t >> 2;
  const int sch = (t & 3) * 8;
  const int vkey = t >> 3;
  const int vch = (t & 7) * 4;
  char* pbase = (char*)Pl + (w << 12);

  const int nkt = (qb + 256) >> 6;  // 4,8,12,16

  if (t < 256) gl16(base + (size_t)skey * 768 + 256 + sch, (char*)Ks[0] + t * 16);
  bf16x4 vv = *(const bf16x4*)(base + (size_t)vkey * 768 + 512 + vch);
  __syncthreads();

  for (int kti = 0; kti < nkt; ++kti) {
    const int kt = kti << 6;
    const int cur = kti & 1;

#pragma unroll
    for (int j = 0; j < 4; ++j) {
      int d = vch + j;
      int byteo = d * (KT * 2) + ((vkey * 2) ^ ((d & 7) << 4));
      *(unsigned short*)((char*)Vt[cur] + byteo) = (unsigned short)vv[j];
    }
    if (kti + 1 < nkt) {
      if (t < 256)
        gl16(base + (size_t)(kt + KT + skey) * 768 + 256 + sch, (char*)Ks[cur ^ 1] + t * 16);
      vv = *(const bf16x4*)(base + (size_t)(kt + KT + vkey) * 768 + 512 + vch);
    }

    const bool active = (kt <= qw + 31);
    if (active) {
      bf16x8 kf[4];
#pragma unroll
      for (int t4 = 0; t4 < 4; ++t4)
        kf[t4] = *(const bf16x8*)&Ks[cur][(t4 * 16 + lr) * 32 + lg * 8];
      f32x4 sc[2][4];
      __builtin_amdgcn_s_setprio(1);
#pragma unroll
      for (int qr = 0; qr < 2; ++qr)
#pragma unroll
        for (int t4 = 0; t4 < 4; ++t4)
          sc[qr][t4] = __builtin_amdgcn_mfma_f32_16x16x32_bf16(
              kf[t4], qf[qr], (f32x4){0.f, 0.f, 0.f, 0.f}, 0, 0, 0);
      __builtin_amdgcn_s_setprio(0);

      if (kt + KT > qw) {
#pragma unroll
        for (int qr = 0; qr < 2; ++qr) {
          int q = qw + qr * 16 + lr;
#pragma unroll
          for (int t4 = 0; t4 < 4; ++t4)
#pragma unroll
            for (int r = 0; r < 4; ++r) {
              int k = kt + t4 * 16 + lg * 4 + r;
              if (k > q) sc[qr][t4][r] = -3.0e38f;
            }
        }
      }

#pragma unroll
      for (int qr = 0; qr < 2; ++qr) {
        float mx = sc[qr][0][0];
#pragma unroll
        for (int t4 = 0; t4 < 4; ++t4)
#pragma unroll
          for (int r = 0; r < 4; ++r) mx = fmaxf(mx, sc[qr][t4][r]);
        mx = fmaxf(mx, __shfl_xor(mx, 16));
        mx = fmaxf(mx, __shfl_xor(mx, 32));
        if (__any(mx > mq[qr] + 8.0f)) {
          float mn = fmaxf(mx, mq[qr]);
          float cf = exp2f((mq[qr] - mn) * Cs);
          mq[qr] = mn;
          lq[qr] *= cf;
#pragma unroll
          for (int r = 0; r < 4; ++r) {
            float cfo = __shfl(cf, (lane & 48) | (lg * 4 + r));
            o[qr][0][r] *= cfo;
            o[qr][1][r] *= cfo;
          }
        }
        float nmxC = -mq[qr] * Cs;
        float ps = 0.f;
#pragma unroll
        for (int t4 = 0; t4 < 4; ++t4)
#pragma unroll
          for (int r = 0; r < 4; ++r) {
            float p = exp2f(fmaf(sc[qr][t4][r], Cs, nmxC));
            sc[qr][t4][r] = p;
            ps += p;
          }
        lq[qr] += ps;
        int ql = qr * 16 + lr;
        int swz = (ql & 7) << 4;
        char* prow = pbase + ql * (KT * 2);
#pragma unroll
        for (int t4 = 0; t4 < 4; ++t4) {
          unsigned lo = cvt_pk_bf16(sc[qr][t4][0], sc[qr][t4][1]);
          unsigned hi = cvt_pk_bf16(sc[qr][t4][2], sc[qr][t4][3]);
          *(uint2*)(prow + ((t4 * 32 + lg * 8) ^ swz)) = make_uint2(lo, hi);
        }
      }
    }

    __syncthreads();

    if (active) {
#pragma unroll
      for (int kp = 0; kp < 2; ++kp) {
        bf16x8 vf[2], pf[2];
        int kb = kp * 64 + lg * 16;
#pragma unroll
        for (int dt = 0; dt < 2; ++dt) {
          int d = dt * 16 + lr;
          vf[dt] = *(const bf16x8*)((char*)Vt[cur] + d * (KT * 2) + (kb ^ ((d & 7) << 4)));
        }
#pragma unroll
        for (int qr = 0; qr < 2; ++qr) {
          int ql = qr * 16 + lr;
          pf[qr] = *(const bf16x8*)(pbase + ql * (KT * 2) + (kb ^ ((ql & 7) << 4)));
        }
        __builtin_amdgcn_s_setprio(1);
#pragma unroll
        for (int qr = 0; qr < 2; ++qr)
#pragma unroll
          for (int dt = 0; dt < 2; ++dt)
            o[qr][dt] = __builtin_amdgcn_mfma_f32_16x16x32_bf16(
                pf[qr], vf[dt], o[qr][dt], 0, 0, 0);
        __builtin_amdgcn_s_setprio(0);
      }
    }
  }

#pragma unroll
  for (int qr = 0; qr < 2; ++qr) {
    float ls = lq[qr];
    ls += __shfl_xor(ls, 16);
    ls += __shfl_xor(ls, 32);
    float invq = 1.0f / ls;
#pragma unroll
    for (int r = 0; r < 4; ++r) {
      float inv = __shfl(invq, (lane & 48) | (lg * 4 + r));
      int q = qw + qr * 16 + lg * 4 + r;
      unsigned short* orow = out + (size_t)(b * S + q) * D + h * HD;
#pragma unroll
      for (int dt = 0; dt < 2; ++dt)
        orow[dt * 16 + lr] = f2bf(o[qr][dt][r] * inv);
    }
  }
}

// ---------------- bf16 MFMA GEMM: C[M,N] = A[M,K] @ W[N,K]^T + bias ----------------
// 128x128 tile, BK=32. EPI: 0=none 1=relu. OUTBF: fp32/bf16 out. SWZ: XCD block swizzle.
template <int EPI, int OUTBF, int SWZ>
__global__ __launch_bounds__(256)
void k_gemm_mfma(const unsigned short* __restrict__ A,
                 const unsigned short* __restrict__ W,
                 const float* __restrict__ bias,
                 void* __restrict__ Cout,
                 int M, int N, int K) {
  __shared__ unsigned short As[128][32];
  __shared__ unsigned short Bs[128][32];
  int t = threadIdx.x;
  int bx = blockIdx.x, by = blockIdx.y;
  if (SWZ) {
    // contiguous row-major chunk per XCD (requires nwg % 8 == 0)
    int nx = gridDim.x;
    int lin = by * nx + bx;
    int q = (nx * (int)gridDim.y) >> 3;
    int nl = (lin & 7) * q + (lin >> 3);
    by = nl / nx;
    bx = nl - by * nx;
  }
  int row0 = by * 128, col0 = bx * 128;
  int wid = t >> 6, lane = t & 63;
  int wr = wid >> 1, wc = wid & 1;
  int lrow = lane & 15, lko = (lane >> 4) * 8;

  f32x4 acc[4][4];
#pragma unroll
  for (int mi = 0; mi < 4; ++mi)
#pragma unroll
    for (int ni = 0; ni < 4; ++ni)
      acc[mi][ni] = (f32x4){0.f, 0.f, 0.f, 0.f};

  int c0 = t, c1 = t + 256;
  int ar0 = c0 >> 2, aq0 = (c0 & 3) * 8;
  int ar1 = c1 >> 2, aq1 = (c1 & 3) * 8;
  int wrow0 = col0 + ar0; if (wrow0 > N - 1) wrow0 = N - 1;
  int wrow1 = col0 + ar1; if (wrow1 > N - 1) wrow1 = N - 1;

  const unsigned short* A0 = A + (size_t)(row0 + ar0) * K + aq0;
  const unsigned short* A1 = A + (size_t)(row0 + ar1) * K + aq1;
  const unsigned short* W0 = W + (size_t)wrow0 * K + aq0;
  const unsigned short* W1 = W + (size_t)wrow1 * K + aq1;

  for (int kt = 0; kt < K; kt += 32) {
    gl16(A0 + kt, (char*)As + c0 * 16);
    gl16(A1 + kt, (char*)As + c1 * 16);
    gl16(W0 + kt, (char*)Bs + c0 * 16);
    gl16(W1 + kt, (char*)Bs + c1 * 16);
    __syncthreads();

    bf16x8 af[4], bfr[4];
#pragma unroll
    for (int mi = 0; mi < 4; ++mi)
      af[mi] = *(const bf16x8*)&As[wr * 64 + mi * 16 + lrow][lko];
#pragma unroll
    for (int ni = 0; ni < 4; ++ni)
      bfr[ni] = *(const bf16x8*)&Bs[wc * 64 + ni * 16 + lrow][lko];
#pragma unroll
    for (int mi = 0; mi < 4; ++mi)
#pragma unroll
      for (int ni = 0; ni < 4; ++ni)
        acc[mi][ni] = __builtin_amdgcn_mfma_f32_16x16x32_bf16(af[mi], bfr[ni], acc[mi][ni], 0, 0, 0);
    __syncthreads();
  }

  int rbase = row0 + wr * 64 + (lane >> 4) * 4;
  int cbase = col0 + wc * 64 + lrow;
#pragma unroll
  for (int ni = 0; ni < 4; ++ni) {
    int c = cbase + ni * 16;
    if (c < N) {
      float bv = bias[c];
#pragma unroll
      for (int mi = 0; mi < 4; ++mi) {
        int rr = rbase + mi * 16;
#pragma unroll
        for (int r = 0; r < 4; ++r) {
          float v = acc[mi][ni][r] + bv;
          if (EPI == 1) v = fmaxf(v, 0.0f);
          size_t off = (size_t)(rr + r) * N + c;
          if (OUTBF)
            ((unsigned short*)Cout)[off] = f2bf(v);
          else
            ((float*)Cout)[off] = v;
        }
      }
    }
  }
}

// ---------------- fused GEMM (N=256) + residual + 1 or 2 LayerNorms ----------------
// Tile 32 rows x 256 cols, 4 waves (one per 64-col chunk), BK=32, double-buffered.
// Grid = M/32 = 512 blocks -> 2 blocks/CU -> 2 waves/SIMD: cross-block TLP hides
// the staging drain (the measured mechanism; in-block vmcnt games don't apply at
// 1 wave/SIMD).
// NLN==1: x = LN(res + A@W^T + bias; g1,b1)
// NLN==2: x1 = LN1(res + A@W^T + bias); x = LN2(x1 + ca[row/S]; g2,b2)
template <int NLN>
__global__ __launch_bounds__(256)
void k_gemm_ln(const unsigned short* __restrict__ A,
               const unsigned short* __restrict__ W,
               const float* __restrict__ bias,
               const float* __restrict__ res,
               const float* __restrict__ ca,
               const float* __restrict__ g1, const float* __restrict__ b1,
               const float* __restrict__ g2, const float* __restrict__ b2,
               float* __restrict__ xout, unsigned short* __restrict__ xb,
               int K) {
  __shared__ unsigned short As[2][32][32];    // 4 KB
  __shared__ unsigned short Bs[2][256][32];   // 32 KB
  __shared__ float red[2][32][4];
  int t = threadIdx.x;
  int row0 = blockIdx.x * 32;
  int wc = t >> 6, lane = t & 63;
  int lr = lane & 15, lg = lane >> 4;

  f32x4 acc[2][4];  // [mi rows][ni cols]
#pragma unroll
  for (int mi = 0; mi < 2; ++mi)
#pragma unroll
    for (int ni = 0; ni < 4; ++ni)
      acc[mi][ni] = (f32x4){0.f, 0.f, 0.f, 0.f};

  // staging per step: As = 128 16B-chunks (threads<128, 1 each), Bs = 1024 (4 each)
  const unsigned short* srcA = nullptr;
  int adoff = 0;
  if (t < 128) {
    int rw = t >> 2, q = (t & 3) * 8;
    srcA = A + (size_t)(row0 + rw) * K + q;
    adoff = t * 16;
  }
  const unsigned short* srcB[4];
  int bdoff[4];
#pragma unroll
  for (int j = 0; j < 4; ++j) {
    int cb = t + (j << 8);
    int rw = cb >> 2, q = (cb & 3) * 8;
    srcB[j] = W + (size_t)rw * K + q;
    bdoff[j] = cb * 16;
  }

  const int nsteps = K >> 5;  // 8 or 32
  // prologue: stage step 0 into buf 0
  if (t < 128) gl16(srcA, (char*)As[0] + adoff);
#pragma unroll
  for (int j = 0; j < 4; ++j) gl16(srcB[j], (char*)Bs[0] + bdoff[j]);
  __syncthreads();

  for (int s = 0; s < nsteps; ++s) {
    const int cur = s & 1;
    if (s + 1 < nsteps) {
      int off = (s + 1) << 5;
      if (t < 128) gl16(srcA + off, (char*)As[cur ^ 1] + adoff);
#pragma unroll
      for (int j = 0; j < 4; ++j) gl16(srcB[j] + off, (char*)Bs[cur ^ 1] + bdoff[j]);
    }
    bf16x8 af[2], bfr[4];
#pragma unroll
    for (int mi = 0; mi < 2; ++mi)
      af[mi] = *(const bf16x8*)&As[cur][mi * 16 + lr][lg * 8];
#pragma unroll
    for (int ni = 0; ni < 4; ++ni)
      bfr[ni] = *(const bf16x8*)&Bs[cur][wc * 64 + ni * 16 + lr][lg * 8];
    __builtin_amdgcn_s_setprio(1);
#pragma unroll
    for (int mi = 0; mi < 2; ++mi)
#pragma unroll
      for (int ni = 0; ni < 4; ++ni)
        acc[mi][ni] = __builtin_amdgcn_mfma_f32_16x16x32_bf16(af[mi], bfr[ni], acc[mi][ni], 0, 0, 0);
    __builtin_amdgcn_s_setprio(0);
    __syncthreads();  // next-tile gl16 drained; cur reads consumed
  }

  // ---- epilogue: v = acc + bias + res; LN over the full 256-col row ----
  int colb = wc * 64 + lr;
  float mean[2][4], rstd[2][4];

#pragma unroll
  for (int mi = 0; mi < 2; ++mi) {
#pragma unroll
    for (int r = 0; r < 4; ++r) {
      int rowl = mi * 16 + lg * 4 + r;
      int rowg = row0 + rowl;
      float s1 = 0.f, s2 = 0.f;
#pragma unroll
      for (int ni = 0; ni < 4; ++ni) {
        int c = colb + ni * 16;
        float v = acc[mi][ni][r] + bias[c] + res[(size_t)rowg * D + c];
        acc[mi][ni][r] = v;
        s1 += v; s2 += v * v;
      }
#pragma unroll
      for (int msk = 1; msk <= 8; msk <<= 1) {
        s1 += __shfl_xor(s1, msk);
        s2 += __shfl_xor(s2, msk);
      }
      if (lr == 0) { red[0][rowl][wc] = s1; red[1][rowl][wc] = s2; }
    }
  }
  __syncthreads();
#pragma unroll
  for (int mi = 0; mi < 2; ++mi)
#pragma unroll
    for (int r = 0; r < 4; ++r) {
      int rowl = mi * 16 + lg * 4 + r;
      f32x4 a = *(const f32x4*)&red[0][rowl][0];
      f32x4 bq = *(const f32x4*)&red[1][rowl][0];
      float s1 = a[0] + a[1] + a[2] + a[3];
      float s2 = bq[0] + bq[1] + bq[2] + bq[3];
      float mn = s1 * (1.0f / D);
      float vr = s2 * (1.0f / D) - mn * mn;
      mean[mi][r] = mn;
      rstd[mi][r] = rsqrtf(vr + 1e-5f);
    }
#pragma unroll
  for (int mi = 0; mi < 2; ++mi)
#pragma unroll
    for (int ni = 0; ni < 4; ++ni) {
      int c = colb + ni * 16;
      float gg = g1[c], bb = b1[c];
#pragma unroll
      for (int r = 0; r < 4; ++r)
        acc[mi][ni][r] = (acc[mi][ni][r] - mean[mi][r]) * rstd[mi][r] * gg + bb;
    }

  if (NLN == 2) {
    __syncthreads();  // red reads done; safe to rewrite
#pragma unroll
    for (int mi = 0; mi < 2; ++mi) {
#pragma unroll
      for (int r = 0; r < 4; ++r) {
        int rowl = mi * 16 + lg * 4 + r;
        int rowg = row0 + rowl;
        int bidx = rowg >> 10;  // row / S
        float s1 = 0.f, s2 = 0.f;
#pragma unroll
        for (int ni = 0; ni < 4; ++ni) {
          int c = colb + ni * 16;
          float v = acc[mi][ni][r] + ca[(size_t)bidx * D + c];
          acc[mi][ni][r] = v;
          s1 += v; s2 += v * v;
        }
#pragma unroll
        for (int msk = 1; msk <= 8; msk <<= 1) {
          s1 += __shfl_xor(s1, msk);
          s2 += __shfl_xor(s2, msk);
        }
        if (lr == 0) { red[0][rowl][wc] = s1; red[1][rowl][wc] = s2; }
      }
    }
    __syncthreads();
#pragma unroll
    for (int mi = 0; mi < 2; ++mi)
#pragma unroll
      for (int r = 0; r < 4; ++r) {
        int rowl = mi * 16 + lg * 4 + r;
        f32x4 a = *(const f32x4*)&red[0][rowl][0];
        f32x4 bq = *(const f32x4*)&red[1][rowl][0];
        float s1 = a[0] + a[1] + a[2] + a[3];
        float s2 = bq[0] + bq[1] + bq[2] + bq[3];
        float mn = s1 * (1.0f / D);
        float vr = s2 * (1.0f / D) - mn * mn;
        mean[mi][r] = mn;
        rstd[mi][r] = rsqrtf(vr + 1e-5f);
      }
#pragma unroll
    for (int mi = 0; mi < 2; ++mi)
#pragma unroll
      for (int ni = 0; ni < 4; ++ni) {
        int c = colb + ni * 16;
        float gg = g2[c], bb = b2[c];
#pragma unroll
        for (int r = 0; r < 4; ++r)
          acc[mi][ni][r] = (acc[mi][ni][r] - mean[mi][r]) * rstd[mi][r] * gg + bb;
      }
  }

  // write x fp32 + bf16 shadow
#pragma unroll
  for (int mi = 0; mi < 2; ++mi)
#pragma unroll
    for (int r = 0; r < 4; ++r) {
      int rowg = row0 + mi * 16 + lg * 4 + r;
#pragma unroll
      for (int ni = 0; ni < 4; ++ni) {
        int c = colb + ni * 16;
        float v = acc[mi][ni][r];
        xout[(size_t)rowg * D + c] = v;
        xb[(size_t)rowg * D + c] = f2bf(v);
      }
    }
}

extern "C" void kernel_launch(void* const* d_in, const int* in_sizes, int n_in,
                              void* d_out, int out_size, void* d_ws, size_t ws_size,
                              hipStream_t stream) {
  (void)in_sizes; (void)n_in; (void)out_size; (void)ws_size;
  const float* tractovka = (const float*)d_in[0];
  const float* context   = (const float*)d_in[1];
  const float* card      = (const float*)d_in[2];
  const float* enc_w     = (const float*)d_in[3];
  const float* enc_b     = (const float*)d_in[4];
  const float* enc_ln_g  = (const float*)d_in[5];
  const float* enc_ln_b  = (const float*)d_in[6];
  const float* fusion_w  = (const float*)d_in[7];
  const float* fusion_b  = (const float*)d_in[8];
  const float* fusion_ln_g = (const float*)d_in[9];
  const float* fusion_ln_b = (const float*)d_in[10];
  const float* tok_emb   = (const float*)d_in[11];
  const float* pos_emb   = (const float*)d_in[12];
  const float* sa_in_w   = (const float*)d_in[13];
  const float* sa_in_b   = (const float*)d_in[14];
  const float* sa_out_w  = (const float*)d_in[15];
  const float* sa_out_b  = (const float*)d_in[16];
  const float* ca_in_w   = (const float*)d_in[17];
  const float* ca_in_b   = (const float*)d_in[18];
  const float* ca_out_w  = (const float*)d_in[19];
  const float* ca_out_b  = (const float*)d_in[20];
  const float* ln1_g     = (const float*)d_in[21];
  const float* ln1_b     = (const float*)d_in[22];
  const float* ln2_g     = (const float*)d_in[23];
  const float* ln2_b     = (const float*)d_in[24];
  const float* ln3_g     = (const float*)d_in[25];
  const float* ln3_b     = (const float*)d_in[26];
  const float* ffn_w1    = (const float*)d_in[27];
  const float* ffn_b1    = (const float*)d_in[28];
  const float* ffn_w2    = (const float*)d_in[29];
  const float* ffn_b2    = (const float*)d_in[30];
  const float* out_w     = (const float*)d_in[31];
  const float* out_b     = (const float*)d_in[32];
  const int*   prev      = (const int*)d_in[33];
  float* out = (float*)d_out;

  const int M = B * S;  // 16384

  float* ws = (float*)d_ws;
  float* x      = ws;                        // M*D f32
  float* bufA   = x + (size_t)M * D;         // M*768 region (QKV bf16; aliased by ffn1b)
  float* bufB   = bufA + (size_t)M * 768;    // M*D f32 (unused, kept for layout)
  float* cat    = bufB + (size_t)M * D;      // B*3D (unused, kept for layout)
  float* mem    = cat + (size_t)B * 3 * D;   // B*D (unused, kept for layout)
  float* ca_add = mem + (size_t)B * D;       // 3*B*D
  unsigned short* xb    = (unsigned short*)(ca_add + (size_t)3 * B * D);  // M*D bf16
  unsigned short* attnb = xb + (size_t)M * D;                             // M*D bf16
  unsigned short* wbf   = attnb + (size_t)M * D;                          // weights bf16
  unsigned short* qkvb  = (unsigned short*)bufA;                          // M*768 bf16
  unsigned short* ffn1b = (unsigned short*)bufA;                          // M*1024 bf16

  const int n_qkvw = 3 * 768 * D;    // 589824
  const int n_outw = 3 * D * D;      // 196608
  const int n_f1w  = 3 * 1024 * D;   // 786432
  const int n_f2w  = 3 * D * 1024;   // 786432
  unsigned short* w_qkv = wbf;
  unsigned short* w_out = w_qkv + n_qkvw;
  unsigned short* w_f1  = w_out + n_outw;
  unsigned short* w_f2  = w_f1 + n_f1w;
  unsigned short* w_v   = w_f2 + n_f2w;

  // all weight conversions in one kernel (dst regions contiguous in wbf)
  k_cvt_all<<<4804, 256, 0, stream>>>(sa_in_w, sa_out_w, ffn_w1, ffn_w2, out_w, wbf);

  // embedding (+bf16 shadow), vectorized
  k_embed<<<M / 4, 256, 0, stream>>>(prev, tok_emb, pos_emb, x, xb);
  // fused encoder side path: enc x3 -> fusion -> ca x3
  k_side<<<B, 256, 0, stream>>>(tractovka, context, card,
                                enc_w, enc_b, enc_ln_g, enc_ln_b,
                                fusion_w, fusion_b, fusion_ln_g, fusion_ln_b,
                                ca_in_w, ca_in_b, ca_out_w, ca_out_b, ca_add);

  for (int l = 0; l < 3; ++l) {
    // QKV: [M,256]@[768,256]^T -> qkvb bf16 [M,768]
    k_gemm_mfma<0, 1, 0><<<dim3(6, M / 128), 256, 0, stream>>>(
        xb, w_qkv + (size_t)l * 768 * D, sa_in_b + (size_t)l * 3 * D, qkvb,
        M, 768, D);
    // causal self-attention (MFMA flash, 256q/block, defer-max) -> attnb bf16
    k_attn6<<<dim3(S / 256, B * H), 512, 0, stream>>>(qkvb, attnb);
    // out-proj + LN1 + (+ca_add) + LN2 fused -> x fp32, xb bf16
    k_gemm_ln<2><<<dim3(M / 32), 256, 0, stream>>>(
        attnb, w_out + (size_t)l * D * D, sa_out_b + (size_t)l * D,
        x, ca_add + (size_t)l * B * D,
        ln1_g + (size_t)l * D, ln1_b + (size_t)l * D,
        ln2_g + (size_t)l * D, ln2_b + (size_t)l * D,
        x, xb, D);
    // FFN1: relu(x@w1^T+b1) -> ffn1b bf16 [M,1024]
    k_gemm_mfma<1, 1, 0><<<dim3(8, M / 128), 256, 0, stream>>>(
        xb, w_f1 + (size_t)l * 1024 * D, ffn_b1 + (size_t)l * 4 * D, ffn1b,
        M, 1024, D);
    // FFN2 + LN3 fused -> x fp32, xb bf16
    k_gemm_ln<1><<<dim3(M / 32), 256, 0, stream>>>(
        ffn1b, w_f2 + (size_t)l * D * 1024, ffn_b2 + (size_t)l * D,
        x, nullptr,
        ln3_g + (size_t)l * D, ln3_b + (size_t)l * D,
        nullptr, nullptr,
        x, xb, 1024);
  }
  // final vocab projection: [M,256]@[10000,256]^T -> out fp32 (XCD-swizzled)
  k_gemm_mfma<0, 0, 1><<<dim3(79, M / 128), 256, 0, stream>>>(
      xb, w_v, out_b, out, M, 10000, D);
}

// Round 7
// 803.674 us; speedup vs baseline: 1.0273x; 1.0039x over previous
//
#include <hip/hip_runtime.h>
#include <math.h>

constexpr int B = 16, S = 1024, D = 256, E = 64, H = 8, HD = 32;

typedef __attribute__((ext_vector_type(8))) short bf16x8;
typedef __attribute__((ext_vector_type(4))) short bf16x4;
typedef __attribute__((ext_vector_type(4))) float f32x4;

__device__ __forceinline__ float gelu_f(float x) {
  return 0.5f * x * (1.0f + erff(x * 0.70710678118654752440f));
}

__device__ __forceinline__ unsigned short f2bf(float f) {
  union { float f; unsigned u; } x; x.f = f;
  unsigned r = x.u + 0x7fff + ((x.u >> 16) & 1);
  return (unsigned short)(r >> 16);
}

// packed f32x2 -> bf16x2 (RNE), low half = a, high half = b
__device__ __forceinline__ unsigned cvt_pk_bf16(float a, float b) {
  unsigned r;
  asm("v_cvt_pk_bf16_f32 %0, %1, %2" : "=v"(r) : "v"(a), "v"(b));
  return r;
}

// async global->LDS, 16B per lane; lds must be wave-uniform-base + lane*16
__device__ __forceinline__ void gl16(const void* g, void* l) {
  __builtin_amdgcn_global_load_lds(
      (const __attribute__((address_space(1))) void*)g,
      (__attribute__((address_space(3))) void*)l, 16, 0, 0);
}

// ---------------- fp32 -> bf16 conversion: ALL weights in one kernel ----------------
// dst regions are laid out contiguously in wbf: qkv | out | f1 | f2 | v
__global__ void k_cvt_all(const float* __restrict__ s0, const float* __restrict__ s1,
                          const float* __restrict__ s2, const float* __restrict__ s3,
                          const float* __restrict__ s4, unsigned short* __restrict__ dst) {
  int i = (blockIdx.x * 256 + threadIdx.x) * 4;
  const float* src;
  int off;
  if (i < 589824)       { src = s0; off = i; }
  else if (i < 786432)  { src = s1; off = i - 589824; }
  else if (i < 1572864) { src = s2; off = i - 786432; }
  else if (i < 2359296) { src = s3; off = i - 1572864; }
  else                  { src = s4; off = i - 2359296; }
  float4 v = *(const float4*)(src + off);
  dst[i + 0] = f2bf(v.x);
  dst[i + 1] = f2bf(v.y);
  dst[i + 2] = f2bf(v.z);
  dst[i + 3] = f2bf(v.w);
}

// ---------------- embedding: x = tok_emb[tok] + pos_emb[s], vectorized ----------------
// 4 rows per block, float4 per thread.
__global__ void k_embed(const int* __restrict__ tok,
                        const float* __restrict__ tok_emb,
                        const float* __restrict__ pos_emb,
                        float* __restrict__ x, unsigned short* __restrict__ xb) {
  int t = threadIdx.x;
  int r = blockIdx.x * 4 + (t >> 6);
  int c4 = (t & 63) * 4;
  int s = r & (S - 1);
  int tk = tok[r];
  float4 te = *(const float4*)(tok_emb + (size_t)tk * D + c4);
  float4 pe = *(const float4*)(pos_emb + (size_t)s * D + c4);
  float4 v = make_float4(te.x + pe.x, te.y + pe.y, te.z + pe.z, te.w + pe.w);
  *(float4*)(x + (size_t)r * D + c4) = v;
  unsigned lo = cvt_pk_bf16(v.x, v.y), hi = cvt_pk_bf16(v.z, v.w);
  *(uint2*)(xb + (size_t)r * D + c4) = make_uint2(lo, hi);
}

// ---------------- fused side path: enc(x3) -> fusion -> ca(x3 layers) ----------------
// One block per batch element b, 256 threads (= feature dim).
__global__ __launch_bounds__(256)
void k_side(const float* __restrict__ tr, const float* __restrict__ ctx,
            const float* __restrict__ card,
            const float* __restrict__ enc_w, const float* __restrict__ enc_b,
            const float* __restrict__ eg, const float* __restrict__ ebt,
            const float* __restrict__ fw, const float* __restrict__ fb,
            const float* __restrict__ fg, const float* __restrict__ fbt,
            const float* __restrict__ ca_in_w, const float* __restrict__ ca_in_b,
            const float* __restrict__ ca_out_w, const float* __restrict__ ca_out_b,
            float* __restrict__ ca_add) {
  int b = blockIdx.x, d = threadIdx.x;
  __shared__ float catl[768], meml[256], vs[256];
  __shared__ float rw1[4], rw2[4];

  auto lnstat = [&](float acc, float& mean, float& rstd) {
    float a1 = acc, a2 = acc * acc;
#pragma unroll
    for (int off = 32; off > 0; off >>= 1) {
      a1 += __shfl_xor(a1, off);
      a2 += __shfl_xor(a2, off);
    }
    int wid = d >> 6, lane = d & 63;
    if (lane == 0) { rw1[wid] = a1; rw2[wid] = a2; }
    __syncthreads();
    float s1 = rw1[0] + rw1[1] + rw1[2] + rw1[3];
    float s2 = rw2[0] + rw2[1] + rw2[2] + rw2[3];
    mean = s1 * (1.0f / D);
    float var = s2 * (1.0f / D) - mean * mean;
    rstd = rsqrtf(var + 1e-5f);
    __syncthreads();  // safe to rewrite rw next call
  };

  // encoders
  for (int i = 0; i < 3; ++i) {
    const float* xin = (i == 0 ? tr : (i == 1 ? ctx : card)) + b * E;
    const float* wr = enc_w + ((size_t)i * D + d) * E;
    float acc = enc_b[i * D + d];
#pragma unroll 8
    for (int e = 0; e < E; ++e) acc += xin[e] * wr[e];
    float mean, rstd;
    lnstat(acc, mean, rstd);
    float nv = (acc - mean) * rstd * eg[i * D + d] + ebt[i * D + d];
    catl[i * D + d] = gelu_f(nv);
  }
  __syncthreads();  // catl complete

  // fusion
  {
    const float* fwr = fw + (size_t)d * 768;
    float fa = fb[d];
    for (int k = 0; k < 768; ++k) fa += catl[k] * fwr[k];
    float mean, rstd;
    lnstat(fa, mean, rstd);
    meml[d] = gelu_f((fa - mean) * rstd * fg[d] + fbt[d]);
  }
  __syncthreads();  // meml complete

  // cross-attn collapsed (softmax over single key == identity), per layer
  for (int l = 0; l < 3; ++l) {
    const float* wi = ca_in_w + ((size_t)l * 768 + 512 + d) * 256;
    float v = ca_in_b[l * 768 + 512 + d];
    for (int k = 0; k < 256; ++k) v += meml[k] * wi[k];
    vs[d] = v;
    __syncthreads();
    const float* wo = ca_out_w + ((size_t)l * 256 + d) * 256;
    float o = ca_out_b[l * 256 + d];
    for (int k = 0; k < 256; ++k) o += vs[k] * wo[k];
    ca_add[((size_t)l * B + b) * 256 + d] = o;
    __syncthreads();  // vs rewrite next l
  }
}

// ---------------- causal flash attention via MFMA, swapped-QK^T softmax ----------------
// 8 waves x 32 queries = 256 queries per block for one (b,h). KT=64 keys/step.
// K/V staged ONCE per block per step; defer-max (T13); diagonal t4-tile skip.
// QK^T computed as mfma(K,Q): C col=lane&15 = q, row=(lane>>4)*4+reg = k.
__global__ __launch_bounds__(512)
void k_attn6(const unsigned short* __restrict__ qkv, unsigned short* __restrict__ out) {
  constexpr int KT = 64;
  __shared__ unsigned short Ks[2][KT * 32];   // [key][32] linear (gl16 dest)
  __shared__ unsigned short Vt[2][32 * KT];   // [d][key], XOR-swizzled rows
  __shared__ unsigned short Pl[8 * 32 * KT];  // per-wave P [q][k], XOR-swizzled

  const int t = threadIdx.x;
  const int w = t >> 6, lane = t & 63;
  const int lg = lane >> 4, lr = lane & 15;
  const int bh = blockIdx.y;
  const int h = bh & (H - 1), b = bh >> 3;
  const int qtile = (int)gridDim.x - 1 - (int)blockIdx.x;  // biggest tiles first
  const int qb = qtile << 8;    // 256 queries per block
  const int qw = qb + w * 32;   // wave query base
  const unsigned short* base = qkv + (size_t)b * S * 768 + h * HD;

  bf16x8 qf[2];
#pragma unroll
  for (int qr = 0; qr < 2; ++qr)
    qf[qr] = *(const bf16x8*)(base + (size_t)(qw + qr * 16 + lr) * 768 + lg * 8);

  f32x4 o[2][2];
#pragma unroll
  for (int qr = 0; qr < 2; ++qr)
#pragma unroll
    for (int dt = 0; dt < 2; ++dt) o[qr][dt] = (f32x4){0.f, 0.f, 0.f, 0.f};
  float mq[2], lq[2];
#pragma unroll
  for (int qr = 0; qr < 2; ++qr) { mq[qr] = -3.0e38f; lq[qr] = 0.f; }

  const float Cs = 0.17677669529663687f * 1.4426950408889634f;  // 1/sqrt(32)*log2(e)

  const int skey = t >> 2;
  const int sch = (t & 3) * 8;
  const int vkey = t >> 3;
  const int vch = (t & 7) * 4;
  char* pbase = (char*)Pl + (w << 12);

  const int nkt = (qb + 256) >> 6;  // 4,8,12,16

  if (t < 256) gl16(base + (size_t)skey * 768 + 256 + sch, (char*)Ks[0] + t * 16);
  bf16x4 vv = *(const bf16x4*)(base + (size_t)vkey * 768 + 512 + vch);
  __syncthreads();

  for (int kti = 0; kti < nkt; ++kti) {
    const int kt = kti << 6;
    const int cur = kti & 1;

#pragma unroll
    for (int j = 0; j < 4; ++j) {
      int d = vch + j;
      int byteo = d * (KT * 2) + ((vkey * 2) ^ ((d & 7) << 4));
      *(unsigned short*)((char*)Vt[cur] + byteo) = (unsigned short)vv[j];
    }
    if (kti + 1 < nkt) {
      if (t < 256)
        gl16(base + (size_t)(kt + KT + skey) * 768 + 256 + sch, (char*)Ks[cur ^ 1] + t * 16);
      vv = *(const bf16x4*)(base + (size_t)(kt + KT + vkey) * 768 + 512 + vch);
    }

    const bool active = (kt <= qw + 31);
    // number of k-subtiles (16 wide) with ANY unmasked element for this wave
    int nvt4 = 4;
    if (active && kt + KT > qw) nvt4 = ((qw + 31 - kt) >> 4) + 1;  // 1..4

    if (active) {
      bf16x8 kf[4];
#pragma unroll
      for (int t4 = 0; t4 < 4; ++t4)
        if (t4 < nvt4)
          kf[t4] = *(const bf16x8*)&Ks[cur][(t4 * 16 + lr) * 32 + lg * 8];
      f32x4 sc[2][4];
      __builtin_amdgcn_s_setprio(1);
#pragma unroll
      for (int qr = 0; qr < 2; ++qr)
#pragma unroll
        for (int t4 = 0; t4 < 4; ++t4)
          if (t4 < nvt4)
            sc[qr][t4] = __builtin_amdgcn_mfma_f32_16x16x32_bf16(
                kf[t4], qf[qr], (f32x4){0.f, 0.f, 0.f, 0.f}, 0, 0, 0);
      __builtin_amdgcn_s_setprio(0);

      // causal mask (partial diagonal tiles only): k = kt+t4*16+lg*4+r, q = qw+qr*16+lr
      if (kt + KT > qw) {
#pragma unroll
        for (int qr = 0; qr < 2; ++qr) {
          int q = qw + qr * 16 + lr;
#pragma unroll
          for (int t4 = 0; t4 < 4; ++t4)
            if (t4 < nvt4)
#pragma unroll
              for (int r = 0; r < 4; ++r) {
                int k = kt + t4 * 16 + lg * 4 + r;
                if (k > q) sc[qr][t4][r] = -3.0e38f;
              }
        }
      }

#pragma unroll
      for (int qr = 0; qr < 2; ++qr) {
        // tree max over valid subtiles (4-deep dep chain)
        float mx = -3.0e38f;
#pragma unroll
        for (int t4 = 0; t4 < 4; ++t4)
          if (t4 < nvt4) {
            float a = fmaxf(fmaxf(sc[qr][t4][0], sc[qr][t4][1]),
                            fmaxf(sc[qr][t4][2], sc[qr][t4][3]));
            mx = fmaxf(mx, a);
          }
        mx = fmaxf(mx, __shfl_xor(mx, 16));
        mx = fmaxf(mx, __shfl_xor(mx, 32));
        if (__any(mx > mq[qr] + 8.0f)) {
          float mn = fmaxf(mx, mq[qr]);
          float cf = exp2f((mq[qr] - mn) * Cs);
          mq[qr] = mn;
          lq[qr] *= cf;
#pragma unroll
          for (int r = 0; r < 4; ++r) {
            float cfo = __shfl(cf, (lane & 48) | (lg * 4 + r));
            o[qr][0][r] *= cfo;
            o[qr][1][r] *= cfo;
          }
        }
        float nmxC = -mq[qr] * Cs;
        float ps = 0.f;
#pragma unroll
        for (int t4 = 0; t4 < 4; ++t4)
#pragma unroll
          for (int r = 0; r < 4; ++r) {
            float p = (t4 < nvt4) ? exp2f(fmaf(sc[qr][t4][r], Cs, nmxC)) : 0.0f;
            sc[qr][t4][r] = p;
            ps += p;
          }
        lq[qr] += ps;
        int ql = qr * 16 + lr;
        int swz = (ql & 7) << 4;
        char* prow = pbase + ql * (KT * 2);
#pragma unroll
        for (int t4 = 0; t4 < 4; ++t4) {
          unsigned lo = cvt_pk_bf16(sc[qr][t4][0], sc[qr][t4][1]);
          unsigned hi = cvt_pk_bf16(sc[qr][t4][2], sc[qr][t4][3]);
          *(uint2*)(prow + ((t4 * 32 + lg * 8) ^ swz)) = make_uint2(lo, hi);
        }
      }
    }

    __syncthreads();

    if (active) {
#pragma unroll
      for (int kp = 0; kp < 2; ++kp) {
        if (kp == 1 && nvt4 <= 2) break;  // keys 32..63 all zero-P: skip pass
        bf16x8 vf[2], pf[2];
        int kb = kp * 64 + lg * 16;
#pragma unroll
        for (int dt = 0; dt < 2; ++dt) {
          int d = dt * 16 + lr;
          vf[dt] = *(const bf16x8*)((char*)Vt[cur] + d * (KT * 2) + (kb ^ ((d & 7) << 4)));
        }
#pragma unroll
        for (int qr = 0; qr < 2; ++qr) {
          int ql = qr * 16 + lr;
          pf[qr] = *(const bf16x8*)(pbase + ql * (KT * 2) + (kb ^ ((ql & 7) << 4)));
        }
        __builtin_amdgcn_s_setprio(1);
#pragma unroll
        for (int qr = 0; qr < 2; ++qr)
#pragma unroll
          for (int dt = 0; dt < 2; ++dt)
            o[qr][dt] = __builtin_amdgcn_mfma_f32_16x16x32_bf16(
                pf[qr], vf[dt], o[qr][dt], 0, 0, 0);
        __builtin_amdgcn_s_setprio(0);
      }
    }
  }

#pragma unroll
  for (int qr = 0; qr < 2; ++qr) {
    float ls = lq[qr];
    ls += __shfl_xor(ls, 16);
    ls += __shfl_xor(ls, 32);
    float invq = 1.0f / ls;
#pragma unroll
    for (int r = 0; r < 4; ++r) {
      float inv = __shfl(invq, (lane & 48) | (lg * 4 + r));
      int q = qw + qr * 16 + lg * 4 + r;
      unsigned short* orow = out + (size_t)(b * S + q) * D + h * HD;
#pragma unroll
      for (int dt = 0; dt < 2; ++dt)
        orow[dt * 16 + lr] = f2bf(o[qr][dt][r] * inv);
    }
  }
}

// ---------------- bf16 MFMA GEMM: C[M,N] = A[M,K] @ W[N,K]^T + bias ----------------
// 128x128 tile, BK=32. EPI: 0=none 1=relu. OUTBF: fp32/bf16 out. SWZ: XCD block swizzle.
template <int EPI, int OUTBF, int SWZ>
__global__ __launch_bounds__(256)
void k_gemm_mfma(const unsigned short* __restrict__ A,
                 const unsigned short* __restrict__ W,
                 const float* __restrict__ bias,
                 void* __restrict__ Cout,
                 int M, int N, int K) {
  __shared__ unsigned short As[128][32];
  __shared__ unsigned short Bs[128][32];
  int t = threadIdx.x;
  int bx = blockIdx.x, by = blockIdx.y;
  if (SWZ) {
    int nx = gridDim.x;
    int lin = by * nx + bx;
    int q = (nx * (int)gridDim.y) >> 3;
    int nl = (lin & 7) * q + (lin >> 3);
    by = nl / nx;
    bx = nl - by * nx;
  }
  int row0 = by * 128, col0 = bx * 128;
  int wid = t >> 6, lane = t & 63;
  int wr = wid >> 1, wc = wid & 1;
  int lrow = lane & 15, lko = (lane >> 4) * 8;

  f32x4 acc[4][4];
#pragma unroll
  for (int mi = 0; mi < 4; ++mi)
#pragma unroll
    for (int ni = 0; ni < 4; ++ni)
      acc[mi][ni] = (f32x4){0.f, 0.f, 0.f, 0.f};

  int c0 = t, c1 = t + 256;
  int ar0 = c0 >> 2, aq0 = (c0 & 3) * 8;
  int ar1 = c1 >> 2, aq1 = (c1 & 3) * 8;
  int wrow0 = col0 + ar0; if (wrow0 > N - 1) wrow0 = N - 1;
  int wrow1 = col0 + ar1; if (wrow1 > N - 1) wrow1 = N - 1;

  const unsigned short* A0 = A + (size_t)(row0 + ar0) * K + aq0;
  const unsigned short* A1 = A + (size_t)(row0 + ar1) * K + aq1;
  const unsigned short* W0 = W + (size_t)wrow0 * K + aq0;
  const unsigned short* W1 = W + (size_t)wrow1 * K + aq1;

  for (int kt = 0; kt < K; kt += 32) {
    gl16(A0 + kt, (char*)As + c0 * 16);
    gl16(A1 + kt, (char*)As + c1 * 16);
    gl16(W0 + kt, (char*)Bs + c0 * 16);
    gl16(W1 + kt, (char*)Bs + c1 * 16);
    __syncthreads();

    bf16x8 af[4], bfr[4];
#pragma unroll
    for (int mi = 0; mi < 4; ++mi)
      af[mi] = *(const bf16x8*)&As[wr * 64 + mi * 16 + lrow][lko];
#pragma unroll
    for (int ni = 0; ni < 4; ++ni)
      bfr[ni] = *(const bf16x8*)&Bs[wc * 64 + ni * 16 + lrow][lko];
#pragma unroll
    for (int mi = 0; mi < 4; ++mi)
#pragma unroll
      for (int ni = 0; ni < 4; ++ni)
        acc[mi][ni] = __builtin_amdgcn_mfma_f32_16x16x32_bf16(af[mi], bfr[ni], acc[mi][ni], 0, 0, 0);
    __syncthreads();
  }

  int rbase = row0 + wr * 64 + (lane >> 4) * 4;
  int cbase = col0 + wc * 64 + lrow;
#pragma unroll
  for (int ni = 0; ni < 4; ++ni) {
    int c = cbase + ni * 16;
    if (c < N) {
      float bv = bias[c];
#pragma unroll
      for (int mi = 0; mi < 4; ++mi) {
        int rr = rbase + mi * 16;
#pragma unroll
        for (int r = 0; r < 4; ++r) {
          float v = acc[mi][ni][r] + bv;
          if (EPI == 1) v = fmaxf(v, 0.0f);
          size_t off = (size_t)(rr + r) * N + c;
          if (OUTBF)
            ((unsigned short*)Cout)[off] = f2bf(v);
          else
            ((float*)Cout)[off] = v;
        }
      }
    }
  }
}

// ---------------- bf16 MFMA GEMM, 256x128 tile (512 thr, 8 waves 4x2) ----------------
// Halves W-side re-fetch vs 128-row tiles (W re-read count = M/rows).
template <int EPI, int OUTBF, int SWZ>
__global__ __launch_bounds__(512)
void k_gemm_mfma2(const unsigned short* __restrict__ A,
                  const unsigned short* __restrict__ W,
                  const float* __restrict__ bias,
                  void* __restrict__ Cout,
                  int M, int N, int K) {
  __shared__ unsigned short As[256][32];
  __shared__ unsigned short Bs[128][32];
  int t = threadIdx.x;
  int bx = blockIdx.x, by = blockIdx.y;
  if (SWZ) {
    int nx = gridDim.x;
    int lin = by * nx + bx;
    int q = (nx * (int)gridDim.y) >> 3;
    int nl = (lin & 7) * q + (lin >> 3);
    by = nl / nx;
    bx = nl - by * nx;
  }
  int row0 = by * 256, col0 = bx * 128;
  int wid = t >> 6, lane = t & 63;
  int wr = wid >> 1, wc = wid & 1;  // wr 0..3 (64-row groups), wc 0..1 (64-col groups)
  int lrow = lane & 15, lko = (lane >> 4) * 8;

  f32x4 acc[4][4];
#pragma unroll
  for (int mi = 0; mi < 4; ++mi)
#pragma unroll
    for (int ni = 0; ni < 4; ++ni)
      acc[mi][ni] = (f32x4){0.f, 0.f, 0.f, 0.f};

  // staging: As 1024 chunks (2/thread), Bs 512 chunks (1/thread)
  int ca0 = t, ca1 = t + 512, cb = t;
  int ar0 = ca0 >> 2, aq0 = (ca0 & 3) * 8;
  int ar1 = ca1 >> 2, aq1 = (ca1 & 3) * 8;
  int wrow = col0 + (cb >> 2); if (wrow > N - 1) wrow = N - 1;
  int wq = (cb & 3) * 8;

  const unsigned short* A0 = A + (size_t)(row0 + ar0) * K + aq0;
  const unsigned short* A1 = A + (size_t)(row0 + ar1) * K + aq1;
  const unsigned short* W0 = W + (size_t)wrow * K + wq;

  for (int kt = 0; kt < K; kt += 32) {
    gl16(A0 + kt, (char*)As + ca0 * 16);
    gl16(A1 + kt, (char*)As + ca1 * 16);
    gl16(W0 + kt, (char*)Bs + cb * 16);
    __syncthreads();

    bf16x8 af[4], bfr[4];
#pragma unroll
    for (int mi = 0; mi < 4; ++mi)
      af[mi] = *(const bf16x8*)&As[wr * 64 + mi * 16 + lrow][lko];
#pragma unroll
    for (int ni = 0; ni < 4; ++ni)
      bfr[ni] = *(const bf16x8*)&Bs[wc * 64 + ni * 16 + lrow][lko];
#pragma unroll
    for (int mi = 0; mi < 4; ++mi)
#pragma unroll
      for (int ni = 0; ni < 4; ++ni)
        acc[mi][ni] = __builtin_amdgcn_mfma_f32_16x16x32_bf16(af[mi], bfr[ni], acc[mi][ni], 0, 0, 0);
    __syncthreads();
  }

  int rbase = row0 + wr * 64 + (lane >> 4) * 4;
  int cbase = col0 + wc * 64 + lrow;
#pragma unroll
  for (int ni = 0; ni < 4; ++ni) {
    int c = cbase + ni * 16;
    if (c < N) {
      float bv = bias[c];
#pragma unroll
      for (int mi = 0; mi < 4; ++mi) {
        int rr = rbase + mi * 16;
#pragma unroll
        for (int r = 0; r < 4; ++r) {
          float v = acc[mi][ni][r] + bv;
          if (EPI == 1) v = fmaxf(v, 0.0f);
          size_t off = (size_t)(rr + r) * N + c;
          if (OUTBF)
            ((unsigned short*)Cout)[off] = f2bf(v);
          else
            ((float*)Cout)[off] = v;
        }
      }
    }
  }
}

// ---------------- fused GEMM (N=256) + residual + 1 or 2 LayerNorms ----------------
// Tile 32 rows x 256 cols, 4 waves (one per 64-col chunk), BK=32, double-buffered.
// Grid = M/32 = 512 blocks -> 2 blocks/CU: cross-block TLP hides the staging drain.
// NLN==1: x = LN(res + A@W^T + bias; g1,b1)
// NLN==2: x1 = LN1(res + A@W^T + bias); x = LN2(x1 + ca[row/S]; g2,b2)
template <int NLN>
__global__ __launch_bounds__(256)
void k_gemm_ln(const unsigned short* __restrict__ A,
               const unsigned short* __restrict__ W,
               const float* __restrict__ bias,
               const float* __restrict__ res,
               const float* __restrict__ ca,
               const float* __restrict__ g1, const float* __restrict__ b1,
               const float* __restrict__ g2, const float* __restrict__ b2,
               float* __restrict__ xout, unsigned short* __restrict__ xb,
               int K) {
  __shared__ unsigned short As[2][32][32];    // 4 KB
  __shared__ unsigned short Bs[2][256][32];   // 32 KB
  __shared__ float red[2][32][4];
  int t = threadIdx.x;
  int row0 = blockIdx.x * 32;
  int wc = t >> 6, lane = t & 63;
  int lr = lane & 15, lg = lane >> 4;

  f32x4 acc[2][4];  // [mi rows][ni cols]
#pragma unroll
  for (int mi = 0; mi < 2; ++mi)
#pragma unroll
    for (int ni = 0; ni < 4; ++ni)
      acc[mi][ni] = (f32x4){0.f, 0.f, 0.f, 0.f};

  // staging per step: As = 128 16B-chunks (threads<128, 1 each), Bs = 1024 (4 each)
  const unsigned short* srcA = nullptr;
  int adoff = 0;
  if (t < 128) {
    int rw = t >> 2, q = (t & 3) * 8;
    srcA = A + (size_t)(row0 + rw) * K + q;
    adoff = t * 16;
  }
  const unsigned short* srcB[4];
  int bdoff[4];
#pragma unroll
  for (int j = 0; j < 4; ++j) {
    int cb = t + (j << 8);
    int rw = cb >> 2, q = (cb & 3) * 8;
    srcB[j] = W + (size_t)rw * K + q;
    bdoff[j] = cb * 16;
  }

  const int nsteps = K >> 5;  // 8 or 32
  if (t < 128) gl16(srcA, (char*)As[0] + adoff);
#pragma unroll
  for (int j = 0; j < 4; ++j) gl16(srcB[j], (char*)Bs[0] + bdoff[j]);
  __syncthreads();

  for (int s = 0; s < nsteps; ++s) {
    const int cur = s & 1;
    if (s + 1 < nsteps) {
      int off = (s + 1) << 5;
      if (t < 128) gl16(srcA + off, (char*)As[cur ^ 1] + adoff);
#pragma unroll
      for (int j = 0; j < 4; ++j) gl16(srcB[j] + off, (char*)Bs[cur ^ 1] + bdoff[j]);
    }
    bf16x8 af[2], bfr[4];
#pragma unroll
    for (int mi = 0; mi < 2; ++mi)
      af[mi] = *(const bf16x8*)&As[cur][mi * 16 + lr][lg * 8];
#pragma unroll
    for (int ni = 0; ni < 4; ++ni)
      bfr[ni] = *(const bf16x8*)&Bs[cur][wc * 64 + ni * 16 + lr][lg * 8];
    __builtin_amdgcn_s_setprio(1);
#pragma unroll
    for (int mi = 0; mi < 2; ++mi)
#pragma unroll
      for (int ni = 0; ni < 4; ++ni)
        acc[mi][ni] = __builtin_amdgcn_mfma_f32_16x16x32_bf16(af[mi], bfr[ni], acc[mi][ni], 0, 0, 0);
    __builtin_amdgcn_s_setprio(0);
    __syncthreads();  // next-tile gl16 drained; cur reads consumed
  }

  // ---- epilogue: v = acc + bias + res; LN over the full 256-col row ----
  int colb = wc * 64 + lr;
  float mean[2][4], rstd[2][4];

#pragma unroll
  for (int mi = 0; mi < 2; ++mi) {
#pragma unroll
    for (int r = 0; r < 4; ++r) {
      int rowl = mi * 16 + lg * 4 + r;
      int rowg = row0 + rowl;
      float s1 = 0.f, s2 = 0.f;
#pragma unroll
      for (int ni = 0; ni < 4; ++ni) {
        int c = colb + ni * 16;
        float v = acc[mi][ni][r] + bias[c] + res[(size_t)rowg * D + c];
        acc[mi][ni][r] = v;
        s1 += v; s2 += v * v;
      }
#pragma unroll
      for (int msk = 1; msk <= 8; msk <<= 1) {
        s1 += __shfl_xor(s1, msk);
        s2 += __shfl_xor(s2, msk);
      }
      if (lr == 0) { red[0][rowl][wc] = s1; red[1][rowl][wc] = s2; }
    }
  }
  __syncthreads();
#pragma unroll
  for (int mi = 0; mi < 2; ++mi)
#pragma unroll
    for (int r = 0; r < 4; ++r) {
      int rowl = mi * 16 + lg * 4 + r;
      f32x4 a = *(const f32x4*)&red[0][rowl][0];
      f32x4 bq = *(const f32x4*)&red[1][rowl][0];
      float s1 = a[0] + a[1] + a[2] + a[3];
      float s2 = bq[0] + bq[1] + bq[2] + bq[3];
      float mn = s1 * (1.0f / D);
      float vr = s2 * (1.0f / D) - mn * mn;
      mean[mi][r] = mn;
      rstd[mi][r] = rsqrtf(vr + 1e-5f);
    }
#pragma unroll
  for (int mi = 0; mi < 2; ++mi)
#pragma unroll
    for (int ni = 0; ni < 4; ++ni) {
      int c = colb + ni * 16;
      float gg = g1[c], bb = b1[c];
#pragma unroll
      for (int r = 0; r < 4; ++r)
        acc[mi][ni][r] = (acc[mi][ni][r] - mean[mi][r]) * rstd[mi][r] * gg + bb;
    }

  if (NLN == 2) {
    __syncthreads();
#pragma unroll
    for (int mi = 0; mi < 2; ++mi) {
#pragma unroll
      for (int r = 0; r < 4; ++r) {
        int rowl = mi * 16 + lg * 4 + r;
        int rowg = row0 + rowl;
        int bidx = rowg >> 10;  // row / S
        float s1 = 0.f, s2 = 0.f;
#pragma unroll
        for (int ni = 0; ni < 4; ++ni) {
          int c = colb + ni * 16;
          float v = acc[mi][ni][r] + ca[(size_t)bidx * D + c];
          acc[mi][ni][r] = v;
          s1 += v; s2 += v * v;
        }
#pragma unroll
        for (int msk = 1; msk <= 8; msk <<= 1) {
          s1 += __shfl_xor(s1, msk);
          s2 += __shfl_xor(s2, msk);
        }
        if (lr == 0) { red[0][rowl][wc] = s1; red[1][rowl][wc] = s2; }
      }
    }
    __syncthreads();
#pragma unroll
    for (int mi = 0; mi < 2; ++mi)
#pragma unroll
      for (int r = 0; r < 4; ++r) {
        int rowl = mi * 16 + lg * 4 + r;
        f32x4 a = *(const f32x4*)&red[0][rowl][0];
        f32x4 bq = *(const f32x4*)&red[1][rowl][0];
        float s1 = a[0] + a[1] + a[2] + a[3];
        float s2 = bq[0] + bq[1] + bq[2] + bq[3];
        float mn = s1 * (1.0f / D);
        float vr = s2 * (1.0f / D) - mn * mn;
        mean[mi][r] = mn;
        rstd[mi][r] = rsqrtf(vr + 1e-5f);
      }
#pragma unroll
    for (int mi = 0; mi < 2; ++mi)
#pragma unroll
      for (int ni = 0; ni < 4; ++ni) {
        int c = colb + ni * 16;
        float gg = g2[c], bb = b2[c];
#pragma unroll
        for (int r = 0; r < 4; ++r)
          acc[mi][ni][r] = (acc[mi][ni][r] - mean[mi][r]) * rstd[mi][r] * gg + bb;
      }
  }

  // write x fp32 + bf16 shadow
#pragma unroll
  for (int mi = 0; mi < 2; ++mi)
#pragma unroll
    for (int r = 0; r < 4; ++r) {
      int rowg = row0 + mi * 16 + lg * 4 + r;
#pragma unroll
      for (int ni = 0; ni < 4; ++ni) {
        int c = colb + ni * 16;
        float v = acc[mi][ni][r];
        xout[(size_t)rowg * D + c] = v;
        xb[(size_t)rowg * D + c] = f2bf(v);
      }
    }
}

extern "C" void kernel_launch(void* const* d_in, const int* in_sizes, int n_in,
                              void* d_out, int out_size, void* d_ws, size_t ws_size,
                              hipStream_t stream) {
  (void)in_sizes; (void)n_in; (void)out_size; (void)ws_size;
  const float* tractovka = (const float*)d_in[0];
  const float* context   = (const float*)d_in[1];
  const float* card      = (const float*)d_in[2];
  const float* enc_w     = (const float*)d_in[3];
  const float* enc_b     = (const float*)d_in[4];
  const float* enc_ln_g  = (const float*)d_in[5];
  const float* enc_ln_b  = (const float*)d_in[6];
  const float* fusion_w  = (const float*)d_in[7];
  const float* fusion_b  = (const float*)d_in[8];
  const float* fusion_ln_g = (const float*)d_in[9];
  const float* fusion_ln_b = (const float*)d_in[10];
  const float* tok_emb   = (const float*)d_in[11];
  const float* pos_emb   = (const float*)d_in[12];
  const float* sa_in_w   = (const float*)d_in[13];
  const float* sa_in_b   = (const float*)d_in[14];
  const float* sa_out_w  = (const float*)d_in[15];
  const float* sa_out_b  = (const float*)d_in[16];
  const float* ca_in_w   = (const float*)d_in[17];
  const float* ca_in_b   = (const float*)d_in[18];
  const float* ca_out_w  = (const float*)d_in[19];
  const float* ca_out_b  = (const float*)d_in[20];
  const float* ln1_g     = (const float*)d_in[21];
  const float* ln1_b     = (const float*)d_in[22];
  const float* ln2_g     = (const float*)d_in[23];
  const float* ln2_b     = (const float*)d_in[24];
  const float* ln3_g     = (const float*)d_in[25];
  const float* ln3_b     = (const float*)d_in[26];
  const float* ffn_w1    = (const float*)d_in[27];
  const float* ffn_b1    = (const float*)d_in[28];
  const float* ffn_w2    = (const float*)d_in[29];
  const float* ffn_b2    = (const float*)d_in[30];
  const float* out_w     = (const float*)d_in[31];
  const float* out_b     = (const float*)d_in[32];
  const int*   prev      = (const int*)d_in[33];
  float* out = (float*)d_out;

  const int M = B * S;  // 16384

  float* ws = (float*)d_ws;
  float* x      = ws;                        // M*D f32
  float* bufA   = x + (size_t)M * D;         // M*768 region (QKV bf16; aliased by ffn1b)
  float* bufB   = bufA + (size_t)M * 768;    // M*D f32 (unused, kept for layout)
  float* cat    = bufB + (size_t)M * D;      // B*3D (unused, kept for layout)
  float* mem    = cat + (size_t)B * 3 * D;   // B*D (unused, kept for layout)
  float* ca_add = mem + (size_t)B * D;       // 3*B*D
  unsigned short* xb    = (unsigned short*)(ca_add + (size_t)3 * B * D);  // M*D bf16
  unsigned short* attnb = xb + (size_t)M * D;                             // M*D bf16
  unsigned short* wbf   = attnb + (size_t)M * D;                          // weights bf16
  unsigned short* qkvb  = (unsigned short*)bufA;                          // M*768 bf16
  unsigned short* ffn1b = (unsigned short*)bufA;                          // M*1024 bf16

  const int n_qkvw = 3 * 768 * D;    // 589824
  const int n_outw = 3 * D * D;      // 196608
  const int n_f1w  = 3 * 1024 * D;   // 786432
  const int n_f2w  = 3 * D * 1024;   // 786432
  unsigned short* w_qkv = wbf;
  unsigned short* w_out = w_qkv + n_qkvw;
  unsigned short* w_f1  = w_out + n_outw;
  unsigned short* w_f2  = w_f1 + n_f1w;
  unsigned short* w_v   = w_f2 + n_f2w;

  // all weight conversions in one kernel (dst regions contiguous in wbf)
  k_cvt_all<<<4804, 256, 0, stream>>>(sa_in_w, sa_out_w, ffn_w1, ffn_w2, out_w, wbf);

  // embedding (+bf16 shadow), vectorized
  k_embed<<<M / 4, 256, 0, stream>>>(prev, tok_emb, pos_emb, x, xb);
  // fused encoder side path: enc x3 -> fusion -> ca x3
  k_side<<<B, 256, 0, stream>>>(tractovka, context, card,
                                enc_w, enc_b, enc_ln_g, enc_ln_b,
                                fusion_w, fusion_b, fusion_ln_g, fusion_ln_b,
                                ca_in_w, ca_in_b, ca_out_w, ca_out_b, ca_add);

  for (int l = 0; l < 3; ++l) {
    // QKV: [M,256]@[768,256]^T -> qkvb bf16 [M,768]  (768 blocks = 3/CU, balanced)
    k_gemm_mfma<0, 1, 0><<<dim3(6, M / 128), 256, 0, stream>>>(
        xb, w_qkv + (size_t)l * 768 * D, sa_in_b + (size_t)l * 3 * D, qkvb,
        M, 768, D);
    // causal self-attention (MFMA flash, 256q/block, defer-max, diag-skip) -> attnb
    k_attn6<<<dim3(S / 256, B * H), 512, 0, stream>>>(qkvb, attnb);
    // out-proj + LN1 + (+ca_add) + LN2 fused -> x fp32, xb bf16
    k_gemm_ln<2><<<dim3(M / 32), 256, 0, stream>>>(
        attnb, w_out + (size_t)l * D * D, sa_out_b + (size_t)l * D,
        x, ca_add + (size_t)l * B * D,
        ln1_g + (size_t)l * D, ln1_b + (size_t)l * D,
        ln2_g + (size_t)l * D, ln2_b + (size_t)l * D,
        x, xb, D);
    // FFN1: relu(x@w1^T+b1) -> ffn1b bf16 [M,1024]  (256-row tile, 512 blocks)
    k_gemm_mfma2<1, 1, 0><<<dim3(8, M / 256), 512, 0, stream>>>(
        xb, w_f1 + (size_t)l * 1024 * D, ffn_b1 + (size_t)l * 4 * D, ffn1b,
        M, 1024, D);
    // FFN2 + LN3 fused -> x fp32, xb bf16
    k_gemm_ln<1><<<dim3(M / 32), 256, 0, stream>>>(
        ffn1b, w_f2 + (size_t)l * D * 1024, ffn_b2 + (size_t)l * D,
        x, nullptr,
        ln3_g + (size_t)l * D, ln3_b + (size_t)l * D,
        nullptr, nullptr,
        x, xb, 1024);
  }
  // final vocab projection: [M,256]@[10000,256]^T -> out fp32
  // 256-row tile halves W re-fetch (640->320 MB); XCD-swizzled (5056 % 8 == 0)
  k_gemm_mfma2<0, 0, 1><<<dim3(79, M / 256), 512, 0, stream>>>(
      xb, w_v, out_b, out, M, 10000, D);
}